// Round 4
// baseline (237.070 us; speedup 1.0000x reference)
//
#include <hip/hip_runtime.h>
#include <hip/hip_bf16.h>
#include <math.h>

typedef _Float16 f16;
typedef _Float16 f16x8 __attribute__((ext_vector_type(8)));
typedef _Float16 f16x4 __attribute__((ext_vector_type(4)));
typedef float f32x4 __attribute__((ext_vector_type(4)));

#define MFMA(a, b, c) __builtin_amdgcn_mfma_f32_16x16x32_f16((a), (b), (c), 0, 0, 0)

constexpr int Dd = 64;
constexpr int Hh = 128;
constexpr int Nn = 4096;
constexpr int NT = 32;
constexpr float SLP = 0.2f;
constexpr float INV2K = 1.0f / 2048.0f;

// Per-d f16 layout in d_ws (element offsets):
//   [0,16384)     W1: h0 (hi 4096|lo 4096 swzK64), h1
//   [16384,49152) W2: h0 (hi 8192|lo 8192 swz), h1
//   [49152,81920) W3: h0, h1
constexpr int PD = 81920;
constexpr size_t W1L_OFF = (size_t)Dd * PD * 2;  // bytes; then w1last f32[64][128]
constexpr size_t WS_NEEDED = W1L_OFF + (size_t)Dd * Hh * 4;

__device__ __forceinline__ int swz(int r, int c) {
  return (r << 7) + ((((c >> 3) ^ (r & 15)) << 3) | (c & 7));
}
__device__ __forceinline__ int swzK64(int r, int c) {
  return (r << 6) + (((((c >> 3) ^ r) & 7) << 3) | (c & 7));
}
__device__ __forceinline__ int swzF(int n, int h) {
  return (n << 7) + ((((h >> 2) ^ n) & 31) << 2) + (h & 3);
}

struct HL { f16 h, l; };
__device__ __forceinline__ HL split(float v) {
  HL r;
  r.h = (f16)v;
  r.l = (f16)((v - (float)r.h) * 2048.0f);
  return r;
}

// Async contiguous global->LDS, 512 threads: nbytes multiple of 8192
__device__ __forceinline__ void cp_lds_async512(const void* g, void* l, int nbytes, int tid) {
  const int lane = tid & 63, wv = tid >> 6;
  for (int base = wv * 1024; base < nbytes; base += 8192) {
    __builtin_amdgcn_global_load_lds(
        (const __attribute__((address_space(1))) void*)((const char*)g + base + lane * 16),
        (__attribute__((address_space(3))) void*)((char*)l + base), 16, 0, 0);
  }
}

// ---------------- preprocess v4: one 16B chunk per thread (R10, verified) ----
__global__ __launch_bounds__(256)
void prep_kernel(const float* __restrict__ W1, const float* __restrict__ W2,
                 const float* __restrict__ W3, f16* __restrict__ wsf,
                 float* __restrict__ w1lg, float* __restrict__ out_log) {
  const int gid = blockIdx.x * 256 + threadIdx.x;  // [0, 655360)
  if (gid < Dd * Hh) w1lg[gid] = W1[(gid >> 7) * 8320 + (gid & 127) * 65 + 64];
  if (gid < Nn) out_log[gid] = 0.f;

  const int d = gid / 10240;
  const int r = gid - d * 10240;
  f16* outd = wsf + (size_t)d * PD;
  float vv[8];
  f16* dst;
  int plane;
  if (r < 2048) {
    int rem = r & 1023;
    int hf = r >> 10;
    plane = rem >> 9;
    int j = rem & 511;
    int row = j >> 3, sc = j & 7;
    int h = hf * 64 + row;
    int k0 = (sc ^ (row & 7)) << 3;
    const float* src = W1 + d * 8320 + h * 65 + k0;
#pragma unroll
    for (int e = 0; e < 8; e++) vv[e] = src[e];
    dst = outd + r * 8;
  } else {
    int r2 = r - 2048;
    int wsec = r2 >> 11;  // 0=W2h0 1=W2h1 2=W3h0 3=W3h1
    int rr = r2 & 2047;
    plane = rr >> 10;
    int j = rr & 1023;
    int row = j >> 4, sc = j & 15;
    int k0 = (sc ^ (row & 15)) << 3;
    const float* base = (wsec < 2 ? W2 : W3) + d * 16384 + (wsec & 1) * 8192;
    const float* src = base + row * 128 + k0;
    float4 v0 = *(const float4*)src, v1 = *(const float4*)(src + 4);
    vv[0] = v0.x; vv[1] = v0.y; vv[2] = v0.z; vv[3] = v0.w;
    vv[4] = v1.x; vv[5] = v1.y; vv[6] = v1.z; vv[7] = v1.w;
    dst = outd + 16384 + (wsec >> 1) * 32768 + (wsec & 1) * 16384 + rr * 8;
  }
  if (plane) {
#pragma unroll
    for (int e = 0; e < 8; e++) {
      f16 hi = (f16)vv[e];
      vv[e] = (vv[e] - (float)hi) * 2048.0f;
    }
  }
  f16x8 o;
#pragma unroll
  for (int e = 0; e < 8; e++) o[e] = (f16)vv[e];
  *(f16x8*)dst = o;
}

// Shared helper: one half-layer of mid-layer MFMAs from weight base wb.
__device__ __forceinline__ void mid_phase(const f16* wb,
                                          const f16x8* axh, const f16x8* axl,
                                          const f16x8* ayh, const f16x8* ayl,
                                          int hr, int quad,
                                          f32x4& aP, f32x4& aS, f32x4& dP, f32x4& dS) {
#pragma unroll
  for (int kc = 0; kc < 4; kc++) {
    int ko = kc * 32 + quad * 8;
    f16x8 wh = *(const f16x8*)&wb[swz(hr, ko)];
    f16x8 wl = *(const f16x8*)&wb[8192 + swz(hr, ko)];
    aP = MFMA(wh, axh[kc], aP);
    aS = MFMA(wl, axh[kc], aS);
    aS = MFMA(wh, axl[kc], aS);
    dP = MFMA(wh, ayh[kc], dP);
    dS = MFMA(wl, ayh[kc], dS);
    dS = MFMA(wh, ayl[kc], dS);
  }
}

// 512 threads (8 waves). R14 (half-step from verified R13): W2h1 is staged
// into the dead act region R0 under the L2-h0 MFMA phase (ping-pong), removing
// one of the two exposed 32KB serial stages. W3h0 staging stays under the L2
// epilogue (R13-verified position); W3h1 stays serial. Minimal structural
// delta to test the R0-ping-pong's safety while capturing ~half the stall.
__global__ __launch_bounds__(512, 4)
void np_prior_fast(const float* __restrict__ x, const f16* __restrict__ wsw,
                   const float* __restrict__ w1lg,
                   const float* __restrict__ b1, const float* __restrict__ b2,
                   const float* __restrict__ b3, const float* __restrict__ W4,
                   const float* __restrict__ b4,
                   float* __restrict__ out_res, float* __restrict__ out_log) {
  __shared__ float4 smem[4096];  // 64 KB: R0 = act (32KB), R1 = Wreg (32KB)
  f16* AH = (f16*)smem;
  f16* AL = AH + NT * 128;
  f16* DH = AL + NT * 128;
  f16* DL = DH + NT * 128;
  f16* R0 = AH;                                  // alias: weight staging slot
  f16* Wreg = (f16*)((char*)smem + 32768);       // R1
  float* A3F = (float*)smem;
  float* D3F = (float*)((char*)smem + 16384);

  const int tid = threadIdx.x, d = blockIdx.y, n0 = blockIdx.x * NT;
  const int lane = tid & 63, wv = tid >> 6, l15 = lane & 15, quad = lane >> 4;
  const int nt = wv & 1, wq = wv >> 1;
  const int ra = nt * 16 + l15;
  const int hr = wq * 16 + l15;

  const f16* wd = wsw + (size_t)d * PD;
  const float* w1l = w1lg + d * Hh;
  const float* b1d = b1 + d * Hh;
  const f32x4 zero = {0.f, 0.f, 0.f, 0.f};

  // Stage ALL of W1 (both halves, 32KB) into R1 once.
  cp_lds_async512(wd, Wreg, 32768, tid);
  {
    int n = tid >> 4, k4 = (tid & 15) << 2;
    int ng = n0 + n, bb = ng >> 8, tt = ng & 255;
    float4 v = *(const float4*)&x[(bb * 257 + tt) * 64 + k4];
    HL a = split(v.x), b = split(v.y), c = split(v.z), e = split(v.w);
    int o = swz(n, k4);
    *(f16x4*)&AH[o] = f16x4{a.h, b.h, c.h, e.h};
    *(f16x4*)&AL[o] = f16x4{a.l, b.l, c.l, e.l};
  }
  float xtv;
  {
    int ng = n0 + ra, bb = ng >> 8, tt = ng & 255;
    xtv = x[(bb * 257 + tt + 1) * 64 + d];
  }
  __syncthreads();  // S1: W1 + x staged

  // ---- Layer 1 (K=64): both halves from R1, no mid-layer staging
  f32x4 l1P[2], l1S[2];
  {
    f16x8 l1xh[2], l1xl[2];
#pragma unroll
    for (int kc = 0; kc < 2; kc++) {
      int ko = kc * 32 + quad * 8;
      l1xh[kc] = *(const f16x8*)&AH[swz(ra, ko)];
      l1xl[kc] = *(const f16x8*)&AL[swz(ra, ko)];
    }
#pragma unroll
    for (int hf = 0; hf < 2; hf++) {
      const f16* wb = Wreg + hf * 8192;
      l1P[hf] = zero; l1S[hf] = zero;
#pragma unroll
      for (int kc = 0; kc < 2; kc++) {
        int ko = kc * 32 + quad * 8;
        f16x8 wh = *(const f16x8*)&wb[swzK64(hr, ko)];
        f16x8 wl = *(const f16x8*)&wb[4096 + swzK64(hr, ko)];
        l1P[hf] = MFMA(wh, l1xh[kc], l1P[hf]);
        l1S[hf] = MFMA(wl, l1xh[kc], l1S[hf]);
        l1S[hf] = MFMA(wh, l1xl[kc], l1S[hf]);
      }
    }
  }
  __syncthreads();                                // S2: R1 (W1) dead
  cp_lds_async512(wd + 16384, Wreg, 32768, tid);  // W2h0 -> R1 (under epilogue)

  // ---- L1 epilogue -> R0
#pragma unroll
  for (int hf = 0; hf < 2; hf++) {
    int hb = hf * 64 + wq * 16 + quad * 4;
    float4 wv4 = *(const float4*)&w1l[hb];
    float4 bv4 = *(const float4*)&b1d[hb];
    f16x4 ah, al, dh, dl;
#pragma unroll
    for (int j = 0; j < 4; j++) {
      float w1j = (&wv4.x)[j];
      float p = l1P[hf][j] + l1S[hf][j] * INV2K + xtv * w1j + (&bv4.x)[j];
      float s = p > 0.f ? 1.f : SLP;
      HL av = split(p * s), dv = split(s * w1j);
      ah[j] = av.h; al[j] = av.l; dh[j] = dv.h; dl[j] = dv.l;
    }
    int o = swz(ra, hb);
    *(f16x4*)&AH[o] = ah; *(f16x4*)&AL[o] = al;
    *(f16x4*)&DH[o] = dh; *(f16x4*)&DL[o] = dl;
  }
  __syncthreads();  // S3: acts ready, W2h0 drained

  // ---- Layer 2: act frags hoisted; W2h1 ping-pong into dead R0
  f32x4 aP[2], aS[2], dP[2], dS[2];
  {
    f16x8 axh[4], axl[4], ayh[4], ayl[4];
#pragma unroll
    for (int kc = 0; kc < 4; kc++) {
      int ko = kc * 32 + quad * 8;
      axh[kc] = *(const f16x8*)&AH[swz(ra, ko)];
      axl[kc] = *(const f16x8*)&AL[swz(ra, ko)];
      ayh[kc] = *(const f16x8*)&DH[swz(ra, ko)];
      ayl[kc] = *(const f16x8*)&DL[swz(ra, ko)];
    }
    __syncthreads();                              // S4: R0 (acts) dead (hoisted)
    cp_lds_async512(wd + 32768, R0, 32768, tid);  // W2h1 -> R0 (under h0 MFMA)
    aP[0] = zero; aS[0] = zero; dP[0] = zero; dS[0] = zero;
    mid_phase(Wreg, axh, axl, ayh, ayl, hr, quad, aP[0], aS[0], dP[0], dS[0]);
    __syncthreads();                              // S5: W2h1 ready (vmcnt drain)
    aP[1] = zero; aS[1] = zero; dP[1] = zero; dS[1] = zero;
    mid_phase(R0, axh, axl, ayh, ayl, hr, quad, aP[1], aS[1], dP[1], dS[1]);
  }
  __syncthreads();                                // S6: R1 (W2h0) + R0 dead
  cp_lds_async512(wd + 49152, Wreg, 32768, tid);  // W3h0 (under epilogue)

  // ---- L2 epilogue -> R0
  {
    const float* b2d = b2 + d * Hh;
#pragma unroll
    for (int hf = 0; hf < 2; hf++) {
      int hb = hf * 64 + wq * 16 + quad * 4;
      float4 bv4 = *(const float4*)&b2d[hb];
      f16x4 ah, al, dh, dl;
#pragma unroll
      for (int j = 0; j < 4; j++) {
        float p = aP[hf][j] + aS[hf][j] * INV2K + (&bv4.x)[j];
        float s = p > 0.f ? 1.f : SLP;
        float dd = s * (dP[hf][j] + dS[hf][j] * INV2K);
        HL av = split(p * s), dv = split(dd);
        ah[j] = av.h; al[j] = av.l; dh[j] = dv.h; dl[j] = dv.l;
      }
      int o = swz(ra, hb);
      *(f16x4*)&AH[o] = ah; *(f16x4*)&AL[o] = al;
      *(f16x4*)&DH[o] = dh; *(f16x4*)&DL[o] = dl;
    }
  }
  __syncthreads();  // S7: acts ready, W3h0 drained

  // ---- Layer 3: act frags hoisted; serial h1 restage (R13 pattern)
  {
    f16x8 axh[4], axl[4], ayh[4], ayl[4];
#pragma unroll
    for (int kc = 0; kc < 4; kc++) {
      int ko = kc * 32 + quad * 8;
      axh[kc] = *(const f16x8*)&AH[swz(ra, ko)];
      axl[kc] = *(const f16x8*)&AL[swz(ra, ko)];
      ayh[kc] = *(const f16x8*)&DH[swz(ra, ko)];
      ayl[kc] = *(const f16x8*)&DL[swz(ra, ko)];
    }
#pragma unroll
    for (int hf = 0; hf < 2; hf++) {
      if (hf == 1) {
        __syncthreads();
        cp_lds_async512(wd + 65536, Wreg, 32768, tid);  // W3h1
        __syncthreads();
      }
      aP[hf] = zero; aS[hf] = zero; dP[hf] = zero; dS[hf] = zero;
      mid_phase(Wreg, axh, axl, ayh, ayl, hr, quad,
                aP[hf], aS[hf], dP[hf], dS[hf]);
    }
  }
  __syncthreads();

  // ---- L3 epilogue -> swizzled f32 overlay (R0)
  {
    const float* b3d = b3 + d * Hh;
#pragma unroll
    for (int hf = 0; hf < 2; hf++) {
      int hb = hf * 64 + wq * 16 + quad * 4;
      float4 bv4 = *(const float4*)&b3d[hb];
      float4 pa, pd;
#pragma unroll
      for (int j = 0; j < 4; j++) {
        float p = aP[hf][j] + aS[hf][j] * INV2K + (&bv4.x)[j];
        float s = p > 0.f ? 1.f : SLP;
        (&pa.x)[j] = p * s;
        (&pd.x)[j] = s * (dP[hf][j] + dS[hf][j] * INV2K);
      }
      *(float4*)&A3F[swzF(ra, hb)] = pa;
      *(float4*)&D3F[swzF(ra, hb)] = pd;
    }
  }
  __syncthreads();

  // ---- Layer 4
  {
    int n = tid >> 4, g16 = tid & 15;
    const float* w4d = W4 + d * Hh;
    int c = g16 * 8;
    float4 va0 = *(const float4*)&A3F[swzF(n, c)];
    float4 va1 = *(const float4*)&A3F[swzF(n, c + 4)];
    float4 vd0 = *(const float4*)&D3F[swzF(n, c)];
    float4 vd1 = *(const float4*)&D3F[swzF(n, c + 4)];
    float4 w0 = *(const float4*)&w4d[c];
    float4 w1 = *(const float4*)&w4d[c + 4];
    float sr = va0.x * w0.x + va0.y * w0.y + va0.z * w0.z + va0.w * w0.w +
               va1.x * w1.x + va1.y * w1.y + va1.z * w1.z + va1.w * w1.w;
    float sd = vd0.x * w0.x + vd0.y * w0.y + vd0.z * w0.z + vd0.w * w0.w +
               vd1.x * w1.x + vd1.y * w1.y + vd1.z * w1.z + vd1.w * w1.w;
    sr += __shfl_xor(sr, 1); sr += __shfl_xor(sr, 2);
    sr += __shfl_xor(sr, 4); sr += __shfl_xor(sr, 8);
    sd += __shfl_xor(sd, 1); sd += __shfl_xor(sd, 2);
    sd += __shfl_xor(sd, 4); sd += __shfl_xor(sd, 8);
    if (g16 == 0) {
      int ng = n0 + n;
      out_res[ng * 64 + d] = sr + b4[d];
      atomicAdd(&out_log[ng], logf(fabsf(sd) + 1e-8f));
    }
  }
}

// ---------------- fallback (no-ws path, 256 threads) -------------------------
__device__ __forceinline__ void stage_wf(f16* WH, f16* WL,
                                         const float* __restrict__ g, int tid) {
  for (int i = tid; i < 2048; i += 256) {
    int h = i >> 5, k4 = (i & 31) << 2;
    float4 v = ((const float4*)g)[i];
    HL a = split(v.x), b = split(v.y), c = split(v.z), e = split(v.w);
    int o = swz(h, k4);
    *(f16x4*)&WH[o] = f16x4{a.h, b.h, c.h, e.h};
    *(f16x4*)&WL[o] = f16x4{a.l, b.l, c.l, e.l};
  }
}

__device__ __forceinline__ void mid_mfma_half(
    const f16* AH, const f16* AL, const f16* DH, const f16* DL,
    const f16* WH, const f16* WL, int nt, int wq, int l15, int quad,
    f32x4* aP, f32x4* aS, f32x4* dP, f32x4* dS) {
#pragma unroll
  for (int kc = 0; kc < 4; kc++) {
    int ko = kc * 32 + quad * 8;
    int ra = nt * 16 + l15;
    f16x8 xh = *(const f16x8*)&AH[swz(ra, ko)];
    f16x8 xl = *(const f16x8*)&AL[swz(ra, ko)];
    f16x8 yh = *(const f16x8*)&DH[swz(ra, ko)];
    f16x8 yl = *(const f16x8*)&DL[swz(ra, ko)];
#pragma unroll
    for (int c2 = 0; c2 < 2; c2++) {
      int hr = (2 * wq + c2) * 16 + l15;
      f16x8 wh = *(const f16x8*)&WH[swz(hr, ko)];
      f16x8 wl = *(const f16x8*)&WL[swz(hr, ko)];
      aP[c2] = MFMA(wh, xh, aP[c2]);
      aS[c2] = MFMA(wl, xh, aS[c2]);
      aS[c2] = MFMA(wh, xl, aS[c2]);
      dP[c2] = MFMA(wh, yh, dP[c2]);
      dS[c2] = MFMA(wl, yh, dS[c2]);
      dS[c2] = MFMA(wh, yl, dS[c2]);
    }
  }
}

__global__ __launch_bounds__(256, 2)
void np_prior_fb(const float* __restrict__ x,
                 const float* __restrict__ W1, const float* __restrict__ b1,
                 const float* __restrict__ W2, const float* __restrict__ b2,
                 const float* __restrict__ W3, const float* __restrict__ b3,
                 const float* __restrict__ W4, const float* __restrict__ b4,
                 float* __restrict__ out_res, float* __restrict__ out_log) {
  __shared__ float4 smem[4096];
  f16* AH = (f16*)smem;
  f16* AL = AH + NT * 128;
  f16* DH = AL + NT * 128;
  f16* DL = DH + NT * 128;
  f16* WHp = (f16*)((char*)smem + 32768);
  f16* WLp = WHp + 64 * 128;
  float* A3F = (float*)smem;
  float* D3F = (float*)((char*)smem + 16384);

  const int tid = threadIdx.x, d = blockIdx.y, n0 = blockIdx.x * NT;
  const int lane = tid & 63, wv = tid >> 6, l15 = lane & 15, quad = lane >> 4;
  const int nt = wv & 1, wq = wv >> 1;

  const float* W1d = W1 + d * Hh * 65;
  const float* b1d = b1 + d * Hh;
  const f32x4 zero = {0.f, 0.f, 0.f, 0.f};

  for (int i = tid; i < NT * 16; i += 256) {
    int n = i >> 4, k4 = (i & 15) << 2;
    int ng = n0 + n, bb = ng >> 8, tt = ng & 255;
    float4 v = *(const float4*)&x[(bb * 257 + tt) * 64 + k4];
    HL a = split(v.x), b = split(v.y), c = split(v.z), e = split(v.w);
    int o = swz(n, k4);
    *(f16x4*)&AH[o] = f16x4{a.h, b.h, c.h, e.h};
    *(f16x4*)&AL[o] = f16x4{a.l, b.l, c.l, e.l};
  }
  float xtv;
  {
    int ng = n0 + nt * 16 + l15, bb = ng >> 8, tt = ng & 255;
    xtv = x[(bb * 257 + tt + 1) * 64 + d];
  }
  for (int i = tid; i < 64 * 64; i += 256) {
    int h = i >> 6, k = i & 63;
    HL s = split(W1d[h * 65 + k]);
    int o = swz(h, k);
    WHp[o] = s.h; WLp[o] = s.l;
  }
  __syncthreads();

  f32x4 l1P[2][2], l1S[2][2];
  for (int hf = 0; hf < 2; hf++) {
    if (hf == 1) {
      __syncthreads();
      for (int i = tid; i < 64 * 64; i += 256) {
        int h = i >> 6, k = i & 63;
        HL s = split(W1d[(64 + h) * 65 + k]);
        int o = swz(h, k);
        WHp[o] = s.h; WLp[o] = s.l;
      }
      __syncthreads();
    }
    l1P[hf][0] = zero; l1P[hf][1] = zero;
    l1S[hf][0] = zero; l1S[hf][1] = zero;
#pragma unroll
    for (int kc = 0; kc < 2; kc++) {
      int ko = kc * 32 + quad * 8;
      f16x8 xh = *(const f16x8*)&AH[swz(nt * 16 + l15, ko)];
      f16x8 xl = *(const f16x8*)&AL[swz(nt * 16 + l15, ko)];
#pragma unroll
      for (int c2 = 0; c2 < 2; c2++) {
        int hr = (2 * wq + c2) * 16 + l15;
        f16x8 wh = *(const f16x8*)&WHp[swz(hr, ko)];
        f16x8 wl = *(const f16x8*)&WLp[swz(hr, ko)];
        l1P[hf][c2] = MFMA(wh, xh, l1P[hf][c2]);
        l1S[hf][c2] = MFMA(wl, xh, l1S[hf][c2]);
        l1S[hf][c2] = MFMA(wh, xl, l1S[hf][c2]);
      }
    }
  }
  __syncthreads();

  {
    int n = nt * 16 + l15;
#pragma unroll
    for (int hf = 0; hf < 2; hf++)
#pragma unroll
      for (int c2 = 0; c2 < 2; c2++) {
        int hb = hf * 64 + (2 * wq + c2) * 16 + quad * 4;
        f16x4 ah, al, dh, dl;
#pragma unroll
        for (int j = 0; j < 4; j++) {
          int h = hb + j;
          float w1j = W1d[h * 65 + 64];
          float p = l1P[hf][c2][j] + l1S[hf][c2][j] * INV2K + xtv * w1j + b1d[h];
          float s = p > 0.f ? 1.f : SLP;
          HL av = split(p * s), dv = split(s * w1j);
          ah[j] = av.h; al[j] = av.l; dh[j] = dv.h; dl[j] = dv.l;
        }
        int o = swz(n, hb);
        *(f16x4*)&AH[o] = ah; *(f16x4*)&AL[o] = al;
        *(f16x4*)&DH[o] = dh; *(f16x4*)&DL[o] = dl;
      }
  }
  stage_wf(WHp, WLp, W2 + d * Hh * Hh, tid);
  __syncthreads();

  f32x4 aP[2][2], aS[2][2], dP[2][2], dS[2][2];
  for (int hf = 0; hf < 2; hf++) {
    if (hf == 1) {
      __syncthreads();
      stage_wf(WHp, WLp, W2 + d * Hh * Hh + 64 * 128, tid);
      __syncthreads();
    }
    aP[hf][0] = zero; aP[hf][1] = zero; aS[hf][0] = zero; aS[hf][1] = zero;
    dP[hf][0] = zero; dP[hf][1] = zero; dS[hf][0] = zero; dS[hf][1] = zero;
    mid_mfma_half(AH, AL, DH, DL, WHp, WLp, nt, wq, l15, quad,
                  aP[hf], aS[hf], dP[hf], dS[hf]);
  }
  __syncthreads();

  {
    const float* b2d = b2 + d * Hh;
    int n = nt * 16 + l15;
#pragma unroll
    for (int hf = 0; hf < 2; hf++)
#pragma unroll
      for (int c2 = 0; c2 < 2; c2++) {
        int hb = hf * 64 + (2 * wq + c2) * 16 + quad * 4;
        f16x4 ah, al, dh, dl;
#pragma unroll
        for (int j = 0; j < 4; j++) {
          int h = hb + j;
          float p = aP[hf][c2][j] + aS[hf][c2][j] * INV2K + b2d[h];
          float s = p > 0.f ? 1.f : SLP;
          float dd = s * (dP[hf][c2][j] + dS[hf][c2][j] * INV2K);
          HL av = split(p * s), dv = split(dd);
          ah[j] = av.h; al[j] = av.l; dh[j] = dv.h; dl[j] = dv.l;
        }
        int o = swz(n, hb);
        *(f16x4*)&AH[o] = ah; *(f16x4*)&AL[o] = al;
        *(f16x4*)&DH[o] = dh; *(f16x4*)&DL[o] = dl;
      }
  }
  stage_wf(WHp, WLp, W3 + d * Hh * Hh, tid);
  __syncthreads();

  for (int hf = 0; hf < 2; hf++) {
    if (hf == 1) {
      __syncthreads();
      stage_wf(WHp, WLp, W3 + d * Hh * Hh + 64 * 128, tid);
      __syncthreads();
    }
    aP[hf][0] = zero; aP[hf][1] = zero; aS[hf][0] = zero; aS[hf][1] = zero;
    dP[hf][0] = zero; dP[hf][1] = zero; dS[hf][0] = zero; dS[hf][1] = zero;
    mid_mfma_half(AH, AL, DH, DL, WHp, WLp, nt, wq, l15, quad,
                  aP[hf], aS[hf], dP[hf], dS[hf]);
  }
  __syncthreads();

  {
    const float* b3d = b3 + d * Hh;
    int n = nt * 16 + l15;
#pragma unroll
    for (int hf = 0; hf < 2; hf++)
#pragma unroll
      for (int c2 = 0; c2 < 2; c2++) {
        int hb = hf * 64 + (2 * wq + c2) * 16 + quad * 4;
        float4 pa, pd;
#pragma unroll
        for (int j = 0; j < 4; j++) {
          int h = hb + j;
          float p = aP[hf][c2][j] + aS[hf][c2][j] * INV2K + b3d[h];
          float s = p > 0.f ? 1.f : SLP;
          (&pa.x)[j] = p * s;
          (&pd.x)[j] = s * (dP[hf][c2][j] + dS[hf][c2][j] * INV2K);
        }
        *(float4*)&A3F[swzF(n, hb)] = pa;
        *(float4*)&D3F[swzF(n, hb)] = pd;
      }
  }
  __syncthreads();

  {
    int n = tid >> 3, oct = tid & 7;
    const float* w4d = W4 + d * Hh;
    float sr = 0.f, sd = 0.f;
#pragma unroll
    for (int i = 0; i < 4; i++) {
      int c = oct * 16 + i * 4;
      float4 va = *(const float4*)&A3F[swzF(n, c)];
      float4 vd = *(const float4*)&D3F[swzF(n, c)];
      float4 w = *(const float4*)&w4d[c];
      sr += va.x * w.x + va.y * w.y + va.z * w.z + va.w * w.w;
      sd += vd.x * w.x + vd.y * w.y + vd.z * w.z + vd.w * w.w;
    }
    sr += __shfl_xor(sr, 1); sr += __shfl_xor(sr, 2); sr += __shfl_xor(sr, 4);
    sd += __shfl_xor(sd, 1); sd += __shfl_xor(sd, 2); sd += __shfl_xor(sd, 4);
    if (oct == 0) {
      int ng = n0 + n;
      out_res[ng * 64 + d] = sr + b4[d];
      atomicAdd(&out_log[ng], logf(fabsf(sd) + 1e-8f));
    }
  }
}

extern "C" void kernel_launch(void* const* d_in, const int* in_sizes, int n_in,
                              void* d_out, int out_size, void* d_ws, size_t ws_size,
                              hipStream_t stream) {
  (void)in_sizes; (void)n_in; (void)out_size;
  const float* x  = (const float*)d_in[0];
  const float* W1 = (const float*)d_in[1];
  const float* b1 = (const float*)d_in[2];
  const float* W2 = (const float*)d_in[3];
  const float* b2 = (const float*)d_in[4];
  const float* W3 = (const float*)d_in[5];
  const float* b3 = (const float*)d_in[6];
  const float* W4 = (const float*)d_in[7];
  const float* b4 = (const float*)d_in[8];

  float* out_res = (float*)d_out;
  float* out_log = out_res + Nn * Dd;

  if (ws_size >= WS_NEEDED) {
    f16* wsf = (f16*)d_ws;
    float* w1lg = (float*)((char*)d_ws + W1L_OFF);
    prep_kernel<<<2560, 256, 0, stream>>>(W1, W2, W3, wsf, w1lg, out_log);
    dim3 grid(Nn / NT, Dd);
    np_prior_fast<<<grid, 512, 0, stream>>>(x, wsf, w1lg, b1, b2, b3, W4, b4,
                                            out_res, out_log);
  } else {
    hipMemsetAsync(out_log, 0, Nn * sizeof(float), stream);
    dim3 grid(Nn / NT, Dd);
    np_prior_fb<<<grid, 256, 0, stream>>>(x, W1, b1, W2, b2, W3, b3, W4, b4,
                                          out_res, out_log);
  }
}

// Round 5
// 236.697 us; speedup vs baseline: 1.0016x; 1.0016x over previous
//
#include <hip/hip_runtime.h>
#include <hip/hip_bf16.h>
#include <math.h>

typedef _Float16 f16;
typedef _Float16 f16x8 __attribute__((ext_vector_type(8)));
typedef _Float16 f16x4 __attribute__((ext_vector_type(4)));
typedef float f32x4 __attribute__((ext_vector_type(4)));

#define MFMA(a, b, c) __builtin_amdgcn_mfma_f32_16x16x32_f16((a), (b), (c), 0, 0, 0)

constexpr int Dd = 64;
constexpr int Hh = 128;
constexpr int Nn = 4096;
constexpr int NT = 32;
constexpr float SLP = 0.2f;
constexpr float INV2K = 1.0f / 2048.0f;

// Per-d f16 layout in d_ws (element offsets):
//   [0,16384)     W1: h0 (hi 4096|lo 4096 swzK64), h1
//   [16384,49152) W2: h0 (hi 8192|lo 8192 swz), h1
//   [49152,81920) W3: h0, h1
constexpr int PD = 81920;
constexpr size_t W1L_OFF = (size_t)Dd * PD * 2;  // bytes; then w1last f32[64][128]
constexpr size_t WS_NEEDED = W1L_OFF + (size_t)Dd * Hh * 4;

__device__ __forceinline__ int swz(int r, int c) {
  return (r << 7) + ((((c >> 3) ^ (r & 15)) << 3) | (c & 7));
}
__device__ __forceinline__ int swzK64(int r, int c) {
  return (r << 6) + (((((c >> 3) ^ r) & 7) << 3) | (c & 7));
}
__device__ __forceinline__ int swzF(int n, int h) {
  return (n << 7) + ((((h >> 2) ^ n) & 31) << 2) + (h & 3);
}

struct HL { f16 h, l; };
__device__ __forceinline__ HL split(float v) {
  HL r;
  r.h = (f16)v;
  r.l = (f16)((v - (float)r.h) * 2048.0f);
  return r;
}

// Async contiguous global->LDS, 512 threads: nbytes multiple of 8192
__device__ __forceinline__ void cp_lds_async512(const void* g, void* l, int nbytes, int tid) {
  const int lane = tid & 63, wv = tid >> 6;
  for (int base = wv * 1024; base < nbytes; base += 8192) {
    __builtin_amdgcn_global_load_lds(
        (const __attribute__((address_space(1))) void*)((const char*)g + base + lane * 16),
        (__attribute__((address_space(3))) void*)((char*)l + base), 16, 0, 0);
  }
}

// Async contiguous global->LDS, 1024 threads: nbytes multiple of 16384
__device__ __forceinline__ void cp_lds_async1024(const void* g, void* l, int nbytes, int tid) {
  const int lane = tid & 63, wv = tid >> 6;
  for (int base = wv * 1024; base < nbytes; base += 16384) {
    __builtin_amdgcn_global_load_lds(
        (const __attribute__((address_space(1))) void*)((const char*)g + base + lane * 16),
        (__attribute__((address_space(3))) void*)((char*)l + base), 16, 0, 0);
  }
}

// ---------------- preprocess v4: one 16B chunk per thread (R10, verified) ----
__global__ __launch_bounds__(256)
void prep_kernel(const float* __restrict__ W1, const float* __restrict__ W2,
                 const float* __restrict__ W3, f16* __restrict__ wsf,
                 float* __restrict__ w1lg, float* __restrict__ out_log) {
  const int gid = blockIdx.x * 256 + threadIdx.x;  // [0, 655360)
  if (gid < Dd * Hh) w1lg[gid] = W1[(gid >> 7) * 8320 + (gid & 127) * 65 + 64];
  if (gid < Nn) out_log[gid] = 0.f;

  const int d = gid / 10240;
  const int r = gid - d * 10240;
  f16* outd = wsf + (size_t)d * PD;
  float vv[8];
  f16* dst;
  int plane;
  if (r < 2048) {
    int rem = r & 1023;
    int hf = r >> 10;
    plane = rem >> 9;
    int j = rem & 511;
    int row = j >> 3, sc = j & 7;
    int h = hf * 64 + row;
    int k0 = (sc ^ (row & 7)) << 3;
    const float* src = W1 + d * 8320 + h * 65 + k0;
#pragma unroll
    for (int e = 0; e < 8; e++) vv[e] = src[e];
    dst = outd + r * 8;
  } else {
    int r2 = r - 2048;
    int wsec = r2 >> 11;  // 0=W2h0 1=W2h1 2=W3h0 3=W3h1
    int rr = r2 & 2047;
    plane = rr >> 10;
    int j = rr & 1023;
    int row = j >> 4, sc = j & 15;
    int k0 = (sc ^ (row & 15)) << 3;
    const float* base = (wsec < 2 ? W2 : W3) + d * 16384 + (wsec & 1) * 8192;
    const float* src = base + row * 128 + k0;
    float4 v0 = *(const float4*)src, v1 = *(const float4*)(src + 4);
    vv[0] = v0.x; vv[1] = v0.y; vv[2] = v0.z; vv[3] = v0.w;
    vv[4] = v1.x; vv[5] = v1.y; vv[6] = v1.z; vv[7] = v1.w;
    dst = outd + 16384 + (wsec >> 1) * 32768 + (wsec & 1) * 16384 + rr * 8;
  }
  if (plane) {
#pragma unroll
    for (int e = 0; e < 8; e++) {
      f16 hi = (f16)vv[e];
      vv[e] = (vv[e] - (float)hi) * 2048.0f;
    }
  }
  f16x8 o;
#pragma unroll
  for (int e = 0; e < 8; e++) o[e] = (f16)vv[e];
  *(f16x8*)dst = o;
}

// Shared helper: one half-layer of mid-layer MFMAs from weight base wb.
__device__ __forceinline__ void mid_phase(const f16* wb,
                                          const f16x8* axh, const f16x8* axl,
                                          const f16x8* ayh, const f16x8* ayl,
                                          int hr, int quad,
                                          f32x4& aP, f32x4& aS, f32x4& dP, f32x4& dS) {
#pragma unroll
  for (int kc = 0; kc < 4; kc++) {
    int ko = kc * 32 + quad * 8;
    f16x8 wh = *(const f16x8*)&wb[swz(hr, ko)];
    f16x8 wl = *(const f16x8*)&wb[8192 + swz(hr, ko)];
    aP = MFMA(wh, axh[kc], aP);
    aS = MFMA(wl, axh[kc], aS);
    aS = MFMA(wh, axl[kc], aS);
    dP = MFMA(wh, ayh[kc], dP);
    dS = MFMA(wl, ayh[kc], dS);
    dS = MFMA(wh, ayl[kc], dS);
  }
}

// R15: NT=64 / 1024 threads / 16 waves / 96KB dynamic LDS / 1 block/CU.
// Per-wave code identical to verified R13/R14; wave map widens to 4nt x 4wq.
// Weight staging traffic per sample HALVES (160KB per 64 samples), barriers
// per sample halve. h1 halves ping-pong into the dead act region (R14-verified
// construct); h0 halves stage under epilogues (R13-verified positions).
__global__ __launch_bounds__(1024, 4)
void np_prior_f64(const float* __restrict__ x, const f16* __restrict__ wsw,
                  const float* __restrict__ w1lg,
                  const float* __restrict__ b1, const float* __restrict__ b2,
                  const float* __restrict__ b3, const float* __restrict__ W4,
                  const float* __restrict__ b4,
                  float* __restrict__ out_res, float* __restrict__ out_log) {
  extern __shared__ char dsm[];          // 98304 B
  f16* AH = (f16*)dsm;                   // [0,16384)B  : 64x128 f16 swz
  f16* AL = AH + 8192;                   // [16384,32768)
  f16* DH = AL + 8192;                   // [32768,49152)
  f16* DL = DH + 8192;                   // [49152,65536)
  f16* R0W = AH;                         // 32KB h1-weight staging slot
  f16* Wreg = (f16*)(dsm + 65536);       // [65536,98304): 32KB weight slot
  float* A3F = (float*)dsm;              // overlay [0,32768): 64x128 f32
  float* D3F = (float*)(dsm + 32768);    // overlay [32768,65536)

  const int tid = threadIdx.x, d = blockIdx.y, n0 = blockIdx.x * 64;
  const int lane = tid & 63, wv = tid >> 6, l15 = lane & 15, quad = lane >> 4;
  const int nt = wv & 3, wq = wv >> 2;
  const int ra = nt * 16 + l15;
  const int hr = wq * 16 + l15;

  const f16* wd = wsw + (size_t)d * PD;
  const float* w1l = w1lg + d * Hh;
  const float* b1d = b1 + d * Hh;
  const f32x4 zero = {0.f, 0.f, 0.f, 0.f};

  cp_lds_async1024(wd, Wreg, 32768, tid);  // W1 full (h0+h1)
  {
    int n = tid >> 4, k4 = (tid & 15) << 2;
    int ng = n0 + n, bb = ng >> 8, tt = ng & 255;
    float4 v = *(const float4*)&x[(bb * 257 + tt) * 64 + k4];
    HL a = split(v.x), b = split(v.y), c = split(v.z), e = split(v.w);
    int o = swz(n, k4);
    *(f16x4*)&AH[o] = f16x4{a.h, b.h, c.h, e.h};
    *(f16x4*)&AL[o] = f16x4{a.l, b.l, c.l, e.l};
  }
  float xtv;
  {
    int ng = n0 + ra, bb = ng >> 8, tt = ng & 255;
    xtv = x[(bb * 257 + tt + 1) * 64 + d];
  }
  __syncthreads();  // S1: W1 + x staged

  // ---- Layer 1 (K=64)
  f32x4 l1P[2], l1S[2];
  {
    f16x8 l1xh[2], l1xl[2];
#pragma unroll
    for (int kc = 0; kc < 2; kc++) {
      int ko = kc * 32 + quad * 8;
      l1xh[kc] = *(const f16x8*)&AH[swz(ra, ko)];
      l1xl[kc] = *(const f16x8*)&AL[swz(ra, ko)];
    }
#pragma unroll
    for (int hf = 0; hf < 2; hf++) {
      const f16* wb = Wreg + hf * 8192;
      l1P[hf] = zero; l1S[hf] = zero;
#pragma unroll
      for (int kc = 0; kc < 2; kc++) {
        int ko = kc * 32 + quad * 8;
        f16x8 wh = *(const f16x8*)&wb[swzK64(hr, ko)];
        f16x8 wl = *(const f16x8*)&wb[4096 + swzK64(hr, ko)];
        l1P[hf] = MFMA(wh, l1xh[kc], l1P[hf]);
        l1S[hf] = MFMA(wl, l1xh[kc], l1S[hf]);
        l1S[hf] = MFMA(wh, l1xl[kc], l1S[hf]);
      }
    }
  }
  __syncthreads();                                 // S2: W1 dead
  cp_lds_async1024(wd + 16384, Wreg, 32768, tid);  // W2h0 (under epilogue)

  // ---- L1 epilogue -> acts
#pragma unroll
  for (int hf = 0; hf < 2; hf++) {
    int hb = hf * 64 + wq * 16 + quad * 4;
    float4 wv4 = *(const float4*)&w1l[hb];
    float4 bv4 = *(const float4*)&b1d[hb];
    f16x4 ah, al, dh, dl;
#pragma unroll
    for (int j = 0; j < 4; j++) {
      float w1j = (&wv4.x)[j];
      float p = l1P[hf][j] + l1S[hf][j] * INV2K + xtv * w1j + (&bv4.x)[j];
      float s = p > 0.f ? 1.f : SLP;
      HL av = split(p * s), dv = split(s * w1j);
      ah[j] = av.h; al[j] = av.l; dh[j] = dv.h; dl[j] = dv.l;
    }
    int o = swz(ra, hb);
    *(f16x4*)&AH[o] = ah; *(f16x4*)&AL[o] = al;
    *(f16x4*)&DH[o] = dh; *(f16x4*)&DL[o] = dl;
  }
  __syncthreads();  // S3: acts ready, W2h0 drained

  // ---- Layer 2: hoist, then ping-pong (W2h1 into dead act region)
  f32x4 aP[2], aS[2], dP[2], dS[2];
  {
    f16x8 axh[4], axl[4], ayh[4], ayl[4];
#pragma unroll
    for (int kc = 0; kc < 4; kc++) {
      int ko = kc * 32 + quad * 8;
      axh[kc] = *(const f16x8*)&AH[swz(ra, ko)];
      axl[kc] = *(const f16x8*)&AL[swz(ra, ko)];
      ayh[kc] = *(const f16x8*)&DH[swz(ra, ko)];
      ayl[kc] = *(const f16x8*)&DL[swz(ra, ko)];
    }
    __syncthreads();                                 // S4: acts hoisted, R0 dead
    cp_lds_async1024(wd + 32768, R0W, 32768, tid);   // W2h1 -> R0 (under h0)
    aP[0] = zero; aS[0] = zero; dP[0] = zero; dS[0] = zero;
    mid_phase(Wreg, axh, axl, ayh, ayl, hr, quad, aP[0], aS[0], dP[0], dS[0]);
    __syncthreads();                                 // S5: W2h1 ready
    aP[1] = zero; aS[1] = zero; dP[1] = zero; dS[1] = zero;
    mid_phase(R0W, axh, axl, ayh, ayl, hr, quad, aP[1], aS[1], dP[1], dS[1]);
  }
  __syncthreads();                                 // S6: MFMAs done, W dead
  cp_lds_async1024(wd + 49152, Wreg, 32768, tid);  // W3h0 (under epilogue)

  // ---- L2 epilogue -> acts
  {
    const float* b2d = b2 + d * Hh;
#pragma unroll
    for (int hf = 0; hf < 2; hf++) {
      int hb = hf * 64 + wq * 16 + quad * 4;
      float4 bv4 = *(const float4*)&b2d[hb];
      f16x4 ah, al, dh, dl;
#pragma unroll
      for (int j = 0; j < 4; j++) {
        float p = aP[hf][j] + aS[hf][j] * INV2K + (&bv4.x)[j];
        float s = p > 0.f ? 1.f : SLP;
        float dd = s * (dP[hf][j] + dS[hf][j] * INV2K);
        HL av = split(p * s), dv = split(dd);
        ah[j] = av.h; al[j] = av.l; dh[j] = dv.h; dl[j] = dv.l;
      }
      int o = swz(ra, hb);
      *(f16x4*)&AH[o] = ah; *(f16x4*)&AL[o] = al;
      *(f16x4*)&DH[o] = dh; *(f16x4*)&DL[o] = dl;
    }
  }
  __syncthreads();  // S7: acts ready, W3h0 drained

  // ---- Layer 3: same ping-pong
  {
    f16x8 axh[4], axl[4], ayh[4], ayl[4];
#pragma unroll
    for (int kc = 0; kc < 4; kc++) {
      int ko = kc * 32 + quad * 8;
      axh[kc] = *(const f16x8*)&AH[swz(ra, ko)];
      axl[kc] = *(const f16x8*)&AL[swz(ra, ko)];
      ayh[kc] = *(const f16x8*)&DH[swz(ra, ko)];
      ayl[kc] = *(const f16x8*)&DL[swz(ra, ko)];
    }
    __syncthreads();                                 // S8: R0 dead
    cp_lds_async1024(wd + 65536, R0W, 32768, tid);   // W3h1 -> R0 (under h0)
    aP[0] = zero; aS[0] = zero; dP[0] = zero; dS[0] = zero;
    mid_phase(Wreg, axh, axl, ayh, ayl, hr, quad, aP[0], aS[0], dP[0], dS[0]);
    __syncthreads();                                 // S9: W3h1 ready
    aP[1] = zero; aS[1] = zero; dP[1] = zero; dS[1] = zero;
    mid_phase(R0W, axh, axl, ayh, ayl, hr, quad, aP[1], aS[1], dP[1], dS[1]);
  }
  __syncthreads();  // S10

  // ---- L3 epilogue -> swizzled f32 overlay
  {
    const float* b3d = b3 + d * Hh;
#pragma unroll
    for (int hf = 0; hf < 2; hf++) {
      int hb = hf * 64 + wq * 16 + quad * 4;
      float4 bv4 = *(const float4*)&b3d[hb];
      float4 pa, pd;
#pragma unroll
      for (int j = 0; j < 4; j++) {
        float p = aP[hf][j] + aS[hf][j] * INV2K + (&bv4.x)[j];
        float s = p > 0.f ? 1.f : SLP;
        (&pa.x)[j] = p * s;
        (&pd.x)[j] = s * (dP[hf][j] + dS[hf][j] * INV2K);
      }
      *(float4*)&A3F[swzF(ra, hb)] = pa;
      *(float4*)&D3F[swzF(ra, hb)] = pd;
    }
  }
  __syncthreads();  // S11

  // ---- Layer 4 (1024 threads: n = tid>>4 covers 64 rows)
  {
    int n = tid >> 4, g16 = tid & 15;
    const float* w4d = W4 + d * Hh;
    int c = g16 * 8;
    float4 va0 = *(const float4*)&A3F[swzF(n, c)];
    float4 va1 = *(const float4*)&A3F[swzF(n, c + 4)];
    float4 vd0 = *(const float4*)&D3F[swzF(n, c)];
    float4 vd1 = *(const float4*)&D3F[swzF(n, c + 4)];
    float4 w0 = *(const float4*)&w4d[c];
    float4 w1 = *(const float4*)&w4d[c + 4];
    float sr = va0.x * w0.x + va0.y * w0.y + va0.z * w0.z + va0.w * w0.w +
               va1.x * w1.x + va1.y * w1.y + va1.z * w1.z + va1.w * w1.w;
    float sd = vd0.x * w0.x + vd0.y * w0.y + vd0.z * w0.z + vd0.w * w0.w +
               vd1.x * w1.x + vd1.y * w1.y + vd1.z * w1.z + vd1.w * w1.w;
    sr += __shfl_xor(sr, 1); sr += __shfl_xor(sr, 2);
    sr += __shfl_xor(sr, 4); sr += __shfl_xor(sr, 8);
    sd += __shfl_xor(sd, 1); sd += __shfl_xor(sd, 2);
    sd += __shfl_xor(sd, 4); sd += __shfl_xor(sd, 8);
    if (g16 == 0) {
      int ng = n0 + n;
      out_res[ng * 64 + d] = sr + b4[d];
      atomicAdd(&out_log[ng], logf(fabsf(sd) + 1e-8f));
    }
  }
}

// ---------------- R13 kernel (verified fallback if big-LDS opt-in fails) ----
__global__ __launch_bounds__(512, 4)
void np_prior_fast(const float* __restrict__ x, const f16* __restrict__ wsw,
                   const float* __restrict__ w1lg,
                   const float* __restrict__ b1, const float* __restrict__ b2,
                   const float* __restrict__ b3, const float* __restrict__ W4,
                   const float* __restrict__ b4,
                   float* __restrict__ out_res, float* __restrict__ out_log) {
  __shared__ float4 smem[4096];  // 64 KB
  f16* AH = (f16*)smem;
  f16* AL = AH + NT * 128;
  f16* DH = AL + NT * 128;
  f16* DL = DH + NT * 128;
  f16* Wreg = (f16*)((char*)smem + 32768);
  float* A3F = (float*)smem;
  float* D3F = (float*)((char*)smem + 16384);

  const int tid = threadIdx.x, d = blockIdx.y, n0 = blockIdx.x * NT;
  const int lane = tid & 63, wv = tid >> 6, l15 = lane & 15, quad = lane >> 4;
  const int nt = wv & 1, wq = wv >> 1;
  const int ra = nt * 16 + l15;
  const int hr = wq * 16 + l15;

  const f16* wd = wsw + (size_t)d * PD;
  const float* w1l = w1lg + d * Hh;
  const float* b1d = b1 + d * Hh;
  const f32x4 zero = {0.f, 0.f, 0.f, 0.f};

  cp_lds_async512(wd, Wreg, 32768, tid);
  {
    int n = tid >> 4, k4 = (tid & 15) << 2;
    int ng = n0 + n, bb = ng >> 8, tt = ng & 255;
    float4 v = *(const float4*)&x[(bb * 257 + tt) * 64 + k4];
    HL a = split(v.x), b = split(v.y), c = split(v.z), e = split(v.w);
    int o = swz(n, k4);
    *(f16x4*)&AH[o] = f16x4{a.h, b.h, c.h, e.h};
    *(f16x4*)&AL[o] = f16x4{a.l, b.l, c.l, e.l};
  }
  float xtv;
  {
    int ng = n0 + ra, bb = ng >> 8, tt = ng & 255;
    xtv = x[(bb * 257 + tt + 1) * 64 + d];
  }
  __syncthreads();

  f32x4 l1P[2], l1S[2];
  {
    f16x8 l1xh[2], l1xl[2];
#pragma unroll
    for (int kc = 0; kc < 2; kc++) {
      int ko = kc * 32 + quad * 8;
      l1xh[kc] = *(const f16x8*)&AH[swz(ra, ko)];
      l1xl[kc] = *(const f16x8*)&AL[swz(ra, ko)];
    }
#pragma unroll
    for (int hf = 0; hf < 2; hf++) {
      const f16* wb = Wreg + hf * 8192;
      l1P[hf] = zero; l1S[hf] = zero;
#pragma unroll
      for (int kc = 0; kc < 2; kc++) {
        int ko = kc * 32 + quad * 8;
        f16x8 wh = *(const f16x8*)&wb[swzK64(hr, ko)];
        f16x8 wl = *(const f16x8*)&wb[4096 + swzK64(hr, ko)];
        l1P[hf] = MFMA(wh, l1xh[kc], l1P[hf]);
        l1S[hf] = MFMA(wl, l1xh[kc], l1S[hf]);
        l1S[hf] = MFMA(wh, l1xl[kc], l1S[hf]);
      }
    }
  }
  __syncthreads();
  cp_lds_async512(wd + 16384, Wreg, 32768, tid);

#pragma unroll
  for (int hf = 0; hf < 2; hf++) {
    int hb = hf * 64 + wq * 16 + quad * 4;
    float4 wv4 = *(const float4*)&w1l[hb];
    float4 bv4 = *(const float4*)&b1d[hb];
    f16x4 ah, al, dh, dl;
#pragma unroll
    for (int j = 0; j < 4; j++) {
      float w1j = (&wv4.x)[j];
      float p = l1P[hf][j] + l1S[hf][j] * INV2K + xtv * w1j + (&bv4.x)[j];
      float s = p > 0.f ? 1.f : SLP;
      HL av = split(p * s), dv = split(s * w1j);
      ah[j] = av.h; al[j] = av.l; dh[j] = dv.h; dl[j] = dv.l;
    }
    int o = swz(ra, hb);
    *(f16x4*)&AH[o] = ah; *(f16x4*)&AL[o] = al;
    *(f16x4*)&DH[o] = dh; *(f16x4*)&DL[o] = dl;
  }
  __syncthreads();

  f32x4 aP[2], aS[2], dP[2], dS[2];
  {
    f16x8 axh[4], axl[4], ayh[4], ayl[4];
#pragma unroll
    for (int kc = 0; kc < 4; kc++) {
      int ko = kc * 32 + quad * 8;
      axh[kc] = *(const f16x8*)&AH[swz(ra, ko)];
      axl[kc] = *(const f16x8*)&AL[swz(ra, ko)];
      ayh[kc] = *(const f16x8*)&DH[swz(ra, ko)];
      ayl[kc] = *(const f16x8*)&DL[swz(ra, ko)];
    }
#pragma unroll
    for (int hf = 0; hf < 2; hf++) {
      if (hf == 1) {
        __syncthreads();
        cp_lds_async512(wd + 32768, Wreg, 32768, tid);
        __syncthreads();
      }
      aP[hf] = zero; aS[hf] = zero; dP[hf] = zero; dS[hf] = zero;
      mid_phase(Wreg, axh, axl, ayh, ayl, hr, quad,
                aP[hf], aS[hf], dP[hf], dS[hf]);
    }
  }
  __syncthreads();
  cp_lds_async512(wd + 49152, Wreg, 32768, tid);

  {
    const float* b2d = b2 + d * Hh;
#pragma unroll
    for (int hf = 0; hf < 2; hf++) {
      int hb = hf * 64 + wq * 16 + quad * 4;
      float4 bv4 = *(const float4*)&b2d[hb];
      f16x4 ah, al, dh, dl;
#pragma unroll
      for (int j = 0; j < 4; j++) {
        float p = aP[hf][j] + aS[hf][j] * INV2K + (&bv4.x)[j];
        float s = p > 0.f ? 1.f : SLP;
        float dd = s * (dP[hf][j] + dS[hf][j] * INV2K);
        HL av = split(p * s), dv = split(dd);
        ah[j] = av.h; al[j] = av.l; dh[j] = dv.h; dl[j] = dv.l;
      }
      int o = swz(ra, hb);
      *(f16x4*)&AH[o] = ah; *(f16x4*)&AL[o] = al;
      *(f16x4*)&DH[o] = dh; *(f16x4*)&DL[o] = dl;
    }
  }
  __syncthreads();

  {
    f16x8 axh[4], axl[4], ayh[4], ayl[4];
#pragma unroll
    for (int kc = 0; kc < 4; kc++) {
      int ko = kc * 32 + quad * 8;
      axh[kc] = *(const f16x8*)&AH[swz(ra, ko)];
      axl[kc] = *(const f16x8*)&AL[swz(ra, ko)];
      ayh[kc] = *(const f16x8*)&DH[swz(ra, ko)];
      ayl[kc] = *(const f16x8*)&DL[swz(ra, ko)];
    }
#pragma unroll
    for (int hf = 0; hf < 2; hf++) {
      if (hf == 1) {
        __syncthreads();
        cp_lds_async512(wd + 65536, Wreg, 32768, tid);
        __syncthreads();
      }
      aP[hf] = zero; aS[hf] = zero; dP[hf] = zero; dS[hf] = zero;
      mid_phase(Wreg, axh, axl, ayh, ayl, hr, quad,
                aP[hf], aS[hf], dP[hf], dS[hf]);
    }
  }
  __syncthreads();

  {
    const float* b3d = b3 + d * Hh;
#pragma unroll
    for (int hf = 0; hf < 2; hf++) {
      int hb = hf * 64 + wq * 16 + quad * 4;
      float4 bv4 = *(const float4*)&b3d[hb];
      float4 pa, pd;
#pragma unroll
      for (int j = 0; j < 4; j++) {
        float p = aP[hf][j] + aS[hf][j] * INV2K + (&bv4.x)[j];
        float s = p > 0.f ? 1.f : SLP;
        (&pa.x)[j] = p * s;
        (&pd.x)[j] = s * (dP[hf][j] + dS[hf][j] * INV2K);
      }
      *(float4*)&A3F[swzF(ra, hb)] = pa;
      *(float4*)&D3F[swzF(ra, hb)] = pd;
    }
  }
  __syncthreads();

  {
    int n = tid >> 4, g16 = tid & 15;
    const float* w4d = W4 + d * Hh;
    int c = g16 * 8;
    float4 va0 = *(const float4*)&A3F[swzF(n, c)];
    float4 va1 = *(const float4*)&A3F[swzF(n, c + 4)];
    float4 vd0 = *(const float4*)&D3F[swzF(n, c)];
    float4 vd1 = *(const float4*)&D3F[swzF(n, c + 4)];
    float4 w0 = *(const float4*)&w4d[c];
    float4 w1 = *(const float4*)&w4d[c + 4];
    float sr = va0.x * w0.x + va0.y * w0.y + va0.z * w0.z + va0.w * w0.w +
               va1.x * w1.x + va1.y * w1.y + va1.z * w1.z + va1.w * w1.w;
    float sd = vd0.x * w0.x + vd0.y * w0.y + vd0.z * w0.z + vd0.w * w0.w +
               vd1.x * w1.x + vd1.y * w1.y + vd1.z * w1.z + vd1.w * w1.w;
    sr += __shfl_xor(sr, 1); sr += __shfl_xor(sr, 2);
    sr += __shfl_xor(sr, 4); sr += __shfl_xor(sr, 8);
    sd += __shfl_xor(sd, 1); sd += __shfl_xor(sd, 2);
    sd += __shfl_xor(sd, 4); sd += __shfl_xor(sd, 8);
    if (g16 == 0) {
      int ng = n0 + n;
      out_res[ng * 64 + d] = sr + b4[d];
      atomicAdd(&out_log[ng], logf(fabsf(sd) + 1e-8f));
    }
  }
}

// ---------------- fallback (no-ws path, 256 threads) -------------------------
__device__ __forceinline__ void stage_wf(f16* WH, f16* WL,
                                         const float* __restrict__ g, int tid) {
  for (int i = tid; i < 2048; i += 256) {
    int h = i >> 5, k4 = (i & 31) << 2;
    float4 v = ((const float4*)g)[i];
    HL a = split(v.x), b = split(v.y), c = split(v.z), e = split(v.w);
    int o = swz(h, k4);
    *(f16x4*)&WH[o] = f16x4{a.h, b.h, c.h, e.h};
    *(f16x4*)&WL[o] = f16x4{a.l, b.l, c.l, e.l};
  }
}

__device__ __forceinline__ void mid_mfma_half(
    const f16* AH, const f16* AL, const f16* DH, const f16* DL,
    const f16* WH, const f16* WL, int nt, int wq, int l15, int quad,
    f32x4* aP, f32x4* aS, f32x4* dP, f32x4* dS) {
#pragma unroll
  for (int kc = 0; kc < 4; kc++) {
    int ko = kc * 32 + quad * 8;
    int ra = nt * 16 + l15;
    f16x8 xh = *(const f16x8*)&AH[swz(ra, ko)];
    f16x8 xl = *(const f16x8*)&AL[swz(ra, ko)];
    f16x8 yh = *(const f16x8*)&DH[swz(ra, ko)];
    f16x8 yl = *(const f16x8*)&DL[swz(ra, ko)];
#pragma unroll
    for (int c2 = 0; c2 < 2; c2++) {
      int hr = (2 * wq + c2) * 16 + l15;
      f16x8 wh = *(const f16x8*)&WH[swz(hr, ko)];
      f16x8 wl = *(const f16x8*)&WL[swz(hr, ko)];
      aP[c2] = MFMA(wh, xh, aP[c2]);
      aS[c2] = MFMA(wl, xh, aS[c2]);
      aS[c2] = MFMA(wh, xl, aS[c2]);
      dP[c2] = MFMA(wh, yh, dP[c2]);
      dS[c2] = MFMA(wl, yh, dS[c2]);
      dS[c2] = MFMA(wh, yl, dS[c2]);
    }
  }
}

__global__ __launch_bounds__(256, 2)
void np_prior_fb(const float* __restrict__ x,
                 const float* __restrict__ W1, const float* __restrict__ b1,
                 const float* __restrict__ W2, const float* __restrict__ b2,
                 const float* __restrict__ W3, const float* __restrict__ b3,
                 const float* __restrict__ W4, const float* __restrict__ b4,
                 float* __restrict__ out_res, float* __restrict__ out_log) {
  __shared__ float4 smem[4096];
  f16* AH = (f16*)smem;
  f16* AL = AH + NT * 128;
  f16* DH = AL + NT * 128;
  f16* DL = DH + NT * 128;
  f16* WHp = (f16*)((char*)smem + 32768);
  f16* WLp = WHp + 64 * 128;
  float* A3F = (float*)smem;
  float* D3F = (float*)((char*)smem + 16384);

  const int tid = threadIdx.x, d = blockIdx.y, n0 = blockIdx.x * NT;
  const int lane = tid & 63, wv = tid >> 6, l15 = lane & 15, quad = lane >> 4;
  const int nt = wv & 1, wq = wv >> 1;

  const float* W1d = W1 + d * Hh * 65;
  const float* b1d = b1 + d * Hh;
  const f32x4 zero = {0.f, 0.f, 0.f, 0.f};

  for (int i = tid; i < NT * 16; i += 256) {
    int n = i >> 4, k4 = (i & 15) << 2;
    int ng = n0 + n, bb = ng >> 8, tt = ng & 255;
    float4 v = *(const float4*)&x[(bb * 257 + tt) * 64 + k4];
    HL a = split(v.x), b = split(v.y), c = split(v.z), e = split(v.w);
    int o = swz(n, k4);
    *(f16x4*)&AH[o] = f16x4{a.h, b.h, c.h, e.h};
    *(f16x4*)&AL[o] = f16x4{a.l, b.l, c.l, e.l};
  }
  float xtv;
  {
    int ng = n0 + nt * 16 + l15, bb = ng >> 8, tt = ng & 255;
    xtv = x[(bb * 257 + tt + 1) * 64 + d];
  }
  for (int i = tid; i < 64 * 64; i += 256) {
    int h = i >> 6, k = i & 63;
    HL s = split(W1d[h * 65 + k]);
    int o = swz(h, k);
    WHp[o] = s.h; WLp[o] = s.l;
  }
  __syncthreads();

  f32x4 l1P[2][2], l1S[2][2];
  for (int hf = 0; hf < 2; hf++) {
    if (hf == 1) {
      __syncthreads();
      for (int i = tid; i < 64 * 64; i += 256) {
        int h = i >> 6, k = i & 63;
        HL s = split(W1d[(64 + h) * 65 + k]);
        int o = swz(h, k);
        WHp[o] = s.h; WLp[o] = s.l;
      }
      __syncthreads();
    }
    l1P[hf][0] = zero; l1P[hf][1] = zero;
    l1S[hf][0] = zero; l1S[hf][1] = zero;
#pragma unroll
    for (int kc = 0; kc < 2; kc++) {
      int ko = kc * 32 + quad * 8;
      f16x8 xh = *(const f16x8*)&AH[swz(nt * 16 + l15, ko)];
      f16x8 xl = *(const f16x8*)&AL[swz(nt * 16 + l15, ko)];
#pragma unroll
      for (int c2 = 0; c2 < 2; c2++) {
        int hr = (2 * wq + c2) * 16 + l15;
        f16x8 wh = *(const f16x8*)&WHp[swz(hr, ko)];
        f16x8 wl = *(const f16x8*)&WLp[swz(hr, ko)];
        l1P[hf][c2] = MFMA(wh, xh, l1P[hf][c2]);
        l1S[hf][c2] = MFMA(wl, xh, l1S[hf][c2]);
        l1S[hf][c2] = MFMA(wh, xl, l1S[hf][c2]);
      }
    }
  }
  __syncthreads();

  {
    int n = nt * 16 + l15;
#pragma unroll
    for (int hf = 0; hf < 2; hf++)
#pragma unroll
      for (int c2 = 0; c2 < 2; c2++) {
        int hb = hf * 64 + (2 * wq + c2) * 16 + quad * 4;
        f16x4 ah, al, dh, dl;
#pragma unroll
        for (int j = 0; j < 4; j++) {
          int h = hb + j;
          float w1j = W1d[h * 65 + 64];
          float p = l1P[hf][c2][j] + l1S[hf][c2][j] * INV2K + xtv * w1j + b1d[h];
          float s = p > 0.f ? 1.f : SLP;
          HL av = split(p * s), dv = split(s * w1j);
          ah[j] = av.h; al[j] = av.l; dh[j] = dv.h; dl[j] = dv.l;
        }
        int o = swz(n, hb);
        *(f16x4*)&AH[o] = ah; *(f16x4*)&AL[o] = al;
        *(f16x4*)&DH[o] = dh; *(f16x4*)&DL[o] = dl;
      }
  }
  stage_wf(WHp, WLp, W2 + d * Hh * Hh, tid);
  __syncthreads();

  f32x4 aP[2][2], aS[2][2], dP[2][2], dS[2][2];
  for (int hf = 0; hf < 2; hf++) {
    if (hf == 1) {
      __syncthreads();
      stage_wf(WHp, WLp, W2 + d * Hh * Hh + 64 * 128, tid);
      __syncthreads();
    }
    aP[hf][0] = zero; aP[hf][1] = zero; aS[hf][0] = zero; aS[hf][1] = zero;
    dP[hf][0] = zero; dP[hf][1] = zero; dS[hf][0] = zero; dS[hf][1] = zero;
    mid_mfma_half(AH, AL, DH, DL, WHp, WLp, nt, wq, l15, quad,
                  aP[hf], aS[hf], dP[hf], dS[hf]);
  }
  __syncthreads();

  {
    const float* b2d = b2 + d * Hh;
    int n = nt * 16 + l15;
#pragma unroll
    for (int hf = 0; hf < 2; hf++)
#pragma unroll
      for (int c2 = 0; c2 < 2; c2++) {
        int hb = hf * 64 + (2 * wq + c2) * 16 + quad * 4;
        f16x4 ah, al, dh, dl;
#pragma unroll
        for (int j = 0; j < 4; j++) {
          int h = hb + j;
          float p = aP[hf][c2][j] + aS[hf][c2][j] * INV2K + b2d[h];
          float s = p > 0.f ? 1.f : SLP;
          float dd = s * (dP[hf][c2][j] + dS[hf][c2][j] * INV2K);
          HL av = split(p * s), dv = split(dd);
          ah[j] = av.h; al[j] = av.l; dh[j] = dv.h; dl[j] = dv.l;
        }
        int o = swz(n, hb);
        *(f16x4*)&AH[o] = ah; *(f16x4*)&AL[o] = al;
        *(f16x4*)&DH[o] = dh; *(f16x4*)&DL[o] = dl;
      }
  }
  stage_wf(WHp, WLp, W3 + d * Hh * Hh, tid);
  __syncthreads();

  for (int hf = 0; hf < 2; hf++) {
    if (hf == 1) {
      __syncthreads();
      stage_wf(WHp, WLp, W3 + d * Hh * Hh + 64 * 128, tid);
      __syncthreads();
    }
    aP[hf][0] = zero; aP[hf][1] = zero; aS[hf][0] = zero; aS[hf][1] = zero;
    dP[hf][0] = zero; dP[hf][1] = zero; dS[hf][0] = zero; dS[hf][1] = zero;
    mid_mfma_half(AH, AL, DH, DL, WHp, WLp, nt, wq, l15, quad,
                  aP[hf], aS[hf], dP[hf], dS[hf]);
  }
  __syncthreads();

  {
    const float* b3d = b3 + d * Hh;
    int n = nt * 16 + l15;
#pragma unroll
    for (int hf = 0; hf < 2; hf++)
#pragma unroll
      for (int c2 = 0; c2 < 2; c2++) {
        int hb = hf * 64 + (2 * wq + c2) * 16 + quad * 4;
        float4 pa, pd;
#pragma unroll
        for (int j = 0; j < 4; j++) {
          int h = hb + j;
          float p = aP[hf][c2][j] + aS[hf][c2][j] * INV2K + b3d[h];
          float s = p > 0.f ? 1.f : SLP;
          (&pa.x)[j] = p * s;
          (&pd.x)[j] = s * (dP[hf][c2][j] + dS[hf][c2][j] * INV2K);
        }
        *(float4*)&A3F[swzF(n, hb)] = pa;
        *(float4*)&D3F[swzF(n, hb)] = pd;
      }
  }
  __syncthreads();

  {
    int n = tid >> 3, oct = tid & 7;
    const float* w4d = W4 + d * Hh;
    float sr = 0.f, sd = 0.f;
#pragma unroll
    for (int i = 0; i < 4; i++) {
      int c = oct * 16 + i * 4;
      float4 va = *(const float4*)&A3F[swzF(n, c)];
      float4 vd = *(const float4*)&D3F[swzF(n, c)];
      float4 w = *(const float4*)&w4d[c];
      sr += va.x * w.x + va.y * w.y + va.z * w.z + va.w * w.w;
      sd += vd.x * w.x + vd.y * w.y + vd.z * w.z + vd.w * w.w;
    }
    sr += __shfl_xor(sr, 1); sr += __shfl_xor(sr, 2); sr += __shfl_xor(sr, 4);
    sd += __shfl_xor(sd, 1); sd += __shfl_xor(sd, 2); sd += __shfl_xor(sd, 4);
    if (oct == 0) {
      int ng = n0 + n;
      out_res[ng * 64 + d] = sr + b4[d];
      atomicAdd(&out_log[ng], logf(fabsf(sd) + 1e-8f));
    }
  }
}

extern "C" void kernel_launch(void* const* d_in, const int* in_sizes, int n_in,
                              void* d_out, int out_size, void* d_ws, size_t ws_size,
                              hipStream_t stream) {
  (void)in_sizes; (void)n_in; (void)out_size;
  const float* x  = (const float*)d_in[0];
  const float* W1 = (const float*)d_in[1];
  const float* b1 = (const float*)d_in[2];
  const float* W2 = (const float*)d_in[3];
  const float* b2 = (const float*)d_in[4];
  const float* W3 = (const float*)d_in[5];
  const float* b3 = (const float*)d_in[6];
  const float* W4 = (const float*)d_in[7];
  const float* b4 = (const float*)d_in[8];

  float* out_res = (float*)d_out;
  float* out_log = out_res + Nn * Dd;

  static int big_lds = -1;  // -1 unknown, 1 ok, 0 failed
  if (big_lds < 0) {
    big_lds = (hipFuncSetAttribute(
                   (const void*)np_prior_f64,
                   hipFuncAttributeMaxDynamicSharedMemorySize, 98304) ==
               hipSuccess)
                  ? 1
                  : 0;
  }

  if (ws_size >= WS_NEEDED) {
    f16* wsf = (f16*)d_ws;
    float* w1lg = (float*)((char*)d_ws + W1L_OFF);
    prep_kernel<<<2560, 256, 0, stream>>>(W1, W2, W3, wsf, w1lg, out_log);
    if (big_lds == 1) {
      dim3 grid(Nn / 64, Dd);
      np_prior_f64<<<grid, 1024, 98304, stream>>>(x, wsf, w1lg, b1, b2, b3,
                                                  W4, b4, out_res, out_log);
    } else {
      dim3 grid(Nn / NT, Dd);
      np_prior_fast<<<grid, 512, 0, stream>>>(x, wsf, w1lg, b1, b2, b3, W4,
                                              b4, out_res, out_log);
    }
  } else {
    hipMemsetAsync(out_log, 0, Nn * sizeof(float), stream);
    dim3 grid(Nn / NT, Dd);
    np_prior_fb<<<grid, 256, 0, stream>>>(x, W1, b1, W2, b2, W3, b3, W4, b4,
                                          out_res, out_log);
  }
}

// Round 6
// 212.190 us; speedup vs baseline: 1.1173x; 1.1155x over previous
//
#include <hip/hip_runtime.h>
#include <hip/hip_bf16.h>
#include <math.h>

typedef _Float16 f16;
typedef _Float16 f16x8 __attribute__((ext_vector_type(8)));
typedef _Float16 f16x4 __attribute__((ext_vector_type(4)));
typedef float f32x4 __attribute__((ext_vector_type(4)));

#define MFMA(a, b, c) __builtin_amdgcn_mfma_f32_16x16x32_f16((a), (b), (c), 0, 0, 0)

constexpr int Dd = 64;
constexpr int Hh = 128;
constexpr int Nn = 4096;
constexpr int NT = 32;  // fb tile
constexpr float SLP = 0.2f;
constexpr float INV2K = 1.0f / 2048.0f;

// Per-d f16 layout in d_ws (element offsets), R16 chunked layout:
//   [0,16384)     W1: c0 = rows 0..63 (hi 4096 swzK64 | lo 4096), c1 = rows 64..127
//   [16384,49152) W2: c0..c3, chunk c = rows 32c..32c+31 (hi 4096 swz | lo 4096)
//   [49152,81920) W3: c0..c3 same
constexpr int PD = 81920;
constexpr size_t W1L_OFF = (size_t)Dd * PD * 2;  // bytes; then w1last f32[64][128]
constexpr size_t WS_NEEDED = W1L_OFF + (size_t)Dd * Hh * 4;

__device__ __forceinline__ int swz(int r, int c) {
  return (r << 7) + ((((c >> 3) ^ (r & 15)) << 3) | (c & 7));
}
__device__ __forceinline__ int swzK64(int r, int c) {
  return (r << 6) + (((((c >> 3) ^ r) & 7) << 3) | (c & 7));
}
__device__ __forceinline__ int swzF(int n, int h) {
  return (n << 7) + ((((h >> 2) ^ n) & 31) << 2) + (h & 3);
}

struct HL { f16 h, l; };
__device__ __forceinline__ HL split(float v) {
  HL r;
  r.h = (f16)v;
  r.l = (f16)((v - (float)r.h) * 2048.0f);
  return r;
}

// Async contiguous global->LDS, 512 threads: nbytes multiple of 8192
__device__ __forceinline__ void cp_lds_async512(const void* g, void* l, int nbytes, int tid) {
  const int lane = tid & 63, wv = tid >> 6;
  for (int base = wv * 1024; base < nbytes; base += 8192) {
    __builtin_amdgcn_global_load_lds(
        (const __attribute__((address_space(1))) void*)((const char*)g + base + lane * 16),
        (__attribute__((address_space(3))) void*)((char*)l + base), 16, 0, 0);
  }
}

// ---------------- preprocess v5: chunked W2/W3 layout (32-row chunks) --------
__global__ __launch_bounds__(256)
void prep_kernel(const float* __restrict__ W1, const float* __restrict__ W2,
                 const float* __restrict__ W3, f16* __restrict__ wsf,
                 float* __restrict__ w1lg, float* __restrict__ out_log) {
  const int gid = blockIdx.x * 256 + threadIdx.x;  // [0, 655360)
  if (gid < Dd * Hh) w1lg[gid] = W1[(gid >> 7) * 8320 + (gid & 127) * 65 + 64];
  if (gid < Nn) out_log[gid] = 0.f;

  const int d = gid / 10240;
  const int r = gid - d * 10240;
  f16* outd = wsf + (size_t)d * PD;
  float vv[8];
  f16* dst;
  int plane;
  if (r < 2048) {
    // W1: unchanged layout (two 64-row chunks, swzK64)
    int rem = r & 1023;
    int hf = r >> 10;
    plane = rem >> 9;
    int j = rem & 511;
    int row = j >> 3, sc = j & 7;
    int h = hf * 64 + row;
    int k0 = (sc ^ (row & 7)) << 3;
    const float* src = W1 + d * 8320 + h * 65 + k0;
#pragma unroll
    for (int e = 0; e < 8; e++) vv[e] = src[e];
    dst = outd + r * 8;
  } else {
    // W2/W3: 4 chunks of 32 rows each; chunk = hi 4096 (swz) | lo 4096
    int r2 = r - 2048;            // [0, 8192)
    int wmat = r2 >> 12;          // 0=W2, 1=W3
    int rr4 = r2 & 4095;
    int chunk = rr4 >> 10;        // 0..3
    int rr = rr4 & 1023;          // within 8192-elem chunk (1024 x 8)
    plane = rr >> 9;
    int j = rr & 511;
    int row = j >> 4, sc = j & 15;  // row 0..31
    int k0 = (sc ^ (row & 15)) << 3;
    const float* srcb = (wmat == 0 ? W2 : W3) + d * 16384;
    const float* src = srcb + (chunk * 32 + row) * 128 + k0;
    float4 v0 = *(const float4*)src, v1 = *(const float4*)(src + 4);
    vv[0] = v0.x; vv[1] = v0.y; vv[2] = v0.z; vv[3] = v0.w;
    vv[4] = v1.x; vv[5] = v1.y; vv[6] = v1.z; vv[7] = v1.w;
    // dst elem offset within chunk = rr*8 = plane*4096 + swz(row, k0)
    dst = outd + 16384 + wmat * 32768 + chunk * 8192 + rr * 8;
  }
  if (plane) {
#pragma unroll
    for (int e = 0; e < 8; e++) {
      f16 hi = (f16)vv[e];
      vv[e] = (vv[e] - (float)hi) * 2048.0f;
    }
  }
  f16x8 o;
#pragma unroll
  for (int e = 0; e < 8; e++) o[e] = (f16)vv[e];
  *(f16x8*)dst = o;
}

// One 32-row weight chunk x full K=128 of MFMAs (hi plane at 0, lo at +4096).
__device__ __forceinline__ void mid_chunk(const f16* ws,
                                          const f16x8* axh, const f16x8* axl,
                                          const f16x8* ayh, const f16x8* ayl,
                                          int hrc, int quad,
                                          f32x4& aP, f32x4& aS, f32x4& dP, f32x4& dS) {
#pragma unroll
  for (int kc = 0; kc < 4; kc++) {
    int ko = kc * 32 + quad * 8;
    f16x8 wh = *(const f16x8*)&ws[swz(hrc, ko)];
    f16x8 wl = *(const f16x8*)&ws[4096 + swz(hrc, ko)];
    aP = MFMA(wh, axh[kc], aP);
    aS = MFMA(wl, axh[kc], aS);
    aS = MFMA(wh, axl[kc], aS);
    dP = MFMA(wh, ayh[kc], dP);
    dS = MFMA(wl, ayh[kc], dS);
    dS = MFMA(wh, ayl[kc], dS);
  }
}

// R16: NT=64, 512 threads (8 waves = 4 n-groups x 2 h-groups), 80KB dynamic
// LDS (acts 64KB + single 16KB weight-chunk slot) -> KEEPS 2 blocks/CU
// (R15's regression was losing that). Per sample: staging traffic halves,
// LDS b128 reads drop 25% (act hoist amortized over 2x samples per weight
// read), MFMA/VALU/barriers unchanged. Per-tile numerics identical to R13.
__global__ __launch_bounds__(512, 4)
void np_prior_v2(const float* __restrict__ x, const f16* __restrict__ wsw,
                 const float* __restrict__ w1lg,
                 const float* __restrict__ b1, const float* __restrict__ b2,
                 const float* __restrict__ b3, const float* __restrict__ W4,
                 const float* __restrict__ b4,
                 float* __restrict__ out_res, float* __restrict__ out_log) {
  extern __shared__ char dsm[];        // 81920 B
  f16* AH = (f16*)dsm;                 // [0,16K): 64x128 f16 swz
  f16* AL = AH + 8192;                 // [16K,32K)
  f16* DH = AL + 8192;                 // [32K,48K)
  f16* DL = DH + 8192;                 // [48K,64K)
  f16* Ws = (f16*)(dsm + 65536);       // [64K,80K): 8192-f16 weight chunk
  float* A3F = (float*)dsm;            // overlay [0,32K): 64x128 f32
  float* D3F = (float*)(dsm + 32768);  // overlay [32K,64K)

  const int tid = threadIdx.x, d = blockIdx.y, n0 = blockIdx.x * 64;
  const int lane = tid & 63, wv = tid >> 6, l15 = lane & 15, quad = lane >> 4;
  const int nt = wv & 3, wq = wv >> 2;  // 4 n-groups x 2 h-groups
  const int ra = nt * 16 + l15;         // 0..63
  const int hrc = wq * 16 + l15;        // 0..31 (row within 32-row chunk)

  const f16* wd = wsw + (size_t)d * PD;
  const float* w1l = w1lg + d * Hh;
  const float* b1d = b1 + d * Hh;
  const f32x4 zero = {0.f, 0.f, 0.f, 0.f};

  // Stage W1 chunk0 (rows 0..63) + x
  cp_lds_async512(wd, Ws, 16384, tid);
  {
    int n = tid >> 3, k8 = (tid & 7) << 3;
    int ng = n0 + n, bb = ng >> 8, tt = ng & 255;
    const float* xs = &x[(bb * 257 + tt) * 64 + k8];
    float4 v0 = *(const float4*)xs, v1 = *(const float4*)(xs + 4);
    float va[8] = {v0.x, v0.y, v0.z, v0.w, v1.x, v1.y, v1.z, v1.w};
    f16x8 vh, vl;
#pragma unroll
    for (int e = 0; e < 8; e++) {
      HL s = split(va[e]);
      vh[e] = s.h; vl[e] = s.l;
    }
    int o = swz(n, k8);
    *(f16x8*)&AH[o] = vh;
    *(f16x8*)&AL[o] = vl;
  }
  float xtv;
  {
    int ng = n0 + ra, bb = ng >> 8, tt = ng & 255;
    xtv = x[(bb * 257 + tt + 1) * 64 + d];
  }
  __syncthreads();  // S1: W1c0 + x staged

  // ---- Layer 1 (K=64), two 64-row chunks through the single slot
  f16x8 l1xh[2], l1xl[2];
#pragma unroll
  for (int kc = 0; kc < 2; kc++) {
    int ko = kc * 32 + quad * 8;
    l1xh[kc] = *(const f16x8*)&AH[swz(ra, ko)];
    l1xl[kc] = *(const f16x8*)&AL[swz(ra, ko)];
  }
#pragma unroll 1
  for (int cf = 0; cf < 2; cf++) {
    f32x4 P[2], S[2];
#pragma unroll
    for (int hf2 = 0; hf2 < 2; hf2++) {
      int hr64 = hf2 * 32 + hrc;
      P[hf2] = zero; S[hf2] = zero;
#pragma unroll
      for (int kc = 0; kc < 2; kc++) {
        int ko = kc * 32 + quad * 8;
        f16x8 wh = *(const f16x8*)&Ws[swzK64(hr64, ko)];
        f16x8 wl = *(const f16x8*)&Ws[4096 + swzK64(hr64, ko)];
        P[hf2] = MFMA(wh, l1xh[kc], P[hf2]);
        S[hf2] = MFMA(wl, l1xh[kc], S[hf2]);
        S[hf2] = MFMA(wh, l1xl[kc], S[hf2]);
      }
    }
    __syncthreads();  // slot dead (x-frags hoisted; MFMAs done)
    // stage next: cf0 -> W1c1; cf1 -> W2c0. Epilogue covers the stage.
    cp_lds_async512(wd + (cf == 0 ? 8192 : 16384), Ws, 16384, tid);
#pragma unroll
    for (int hf2 = 0; hf2 < 2; hf2++) {
      int hb = cf * 64 + hf2 * 32 + wq * 16 + quad * 4;
      float4 wv4 = *(const float4*)&w1l[hb];
      float4 bv4 = *(const float4*)&b1d[hb];
      f16x4 ah, al, dh, dl;
#pragma unroll
      for (int j = 0; j < 4; j++) {
        float w1j = (&wv4.x)[j];
        float p = P[hf2][j] + S[hf2][j] * INV2K + xtv * w1j + (&bv4.x)[j];
        float s = p > 0.f ? 1.f : SLP;
        HL av = split(p * s), dv = split(s * w1j);
        ah[j] = av.h; al[j] = av.l; dh[j] = dv.h; dl[j] = dv.l;
      }
      int o = swz(ra, hb);
      *(f16x4*)&AH[o] = ah; *(f16x4*)&AL[o] = al;
      *(f16x4*)&DH[o] = dh; *(f16x4*)&DL[o] = dl;
    }
    __syncthreads();  // stage drained; epi visible
  }
  // here: acts(L1) ready, Ws = W2c0

  // ---- Layer 2: hoist acts once, then 4 weight chunks through the slot
  {
    f16x8 axh[4], axl[4], ayh[4], ayl[4];
#pragma unroll
    for (int kc = 0; kc < 4; kc++) {
      int ko = kc * 32 + quad * 8;
      axh[kc] = *(const f16x8*)&AH[swz(ra, ko)];
      axl[kc] = *(const f16x8*)&AL[swz(ra, ko)];
      ayh[kc] = *(const f16x8*)&DH[swz(ra, ko)];
      ayl[kc] = *(const f16x8*)&DL[swz(ra, ko)];
    }
    __syncthreads();  // hoists done, act LDS dead
    const float* b2d = b2 + d * Hh;
#pragma unroll 1
    for (int c = 0; c < 4; c++) {
      if (c > 0) {
        __syncthreads();
        cp_lds_async512(wd + 16384 + c * 8192, Ws, 16384, tid);
        __syncthreads();
      }
      f32x4 aP = zero, aS = zero, dP = zero, dS = zero;
      mid_chunk(Ws, axh, axl, ayh, ayl, hrc, quad, aP, aS, dP, dS);
      {
        int hb = c * 32 + wq * 16 + quad * 4;
        float4 bv4 = *(const float4*)&b2d[hb];
        f16x4 ah, al, dh, dl;
#pragma unroll
        for (int j = 0; j < 4; j++) {
          float p = aP[j] + aS[j] * INV2K + (&bv4.x)[j];
          float s = p > 0.f ? 1.f : SLP;
          float dd = s * (dP[j] + dS[j] * INV2K);
          HL av = split(p * s), dv = split(dd);
          ah[j] = av.h; al[j] = av.l; dh[j] = dv.h; dl[j] = dv.l;
        }
        int o = swz(ra, hb);
        *(f16x4*)&AH[o] = ah; *(f16x4*)&AL[o] = al;
        *(f16x4*)&DH[o] = dh; *(f16x4*)&DL[o] = dl;
      }
    }
  }
  __syncthreads();                                // L2 done; slot dead
  cp_lds_async512(wd + 49152, Ws, 16384, tid);    // W3c0 (under L3 hoist)

  // ---- Layer 3: same, epilogue -> swizzled f32 overlay
  {
    f16x8 axh[4], axl[4], ayh[4], ayl[4];
#pragma unroll
    for (int kc = 0; kc < 4; kc++) {
      int ko = kc * 32 + quad * 8;
      axh[kc] = *(const f16x8*)&AH[swz(ra, ko)];
      axl[kc] = *(const f16x8*)&AL[swz(ra, ko)];
      ayh[kc] = *(const f16x8*)&DH[swz(ra, ko)];
      ayl[kc] = *(const f16x8*)&DL[swz(ra, ko)];
    }
    __syncthreads();  // W3c0 drained + hoists done
    const float* b3d = b3 + d * Hh;
#pragma unroll 1
    for (int c = 0; c < 4; c++) {
      if (c > 0) {
        __syncthreads();
        cp_lds_async512(wd + 49152 + c * 8192, Ws, 16384, tid);
        __syncthreads();
      }
      f32x4 aP = zero, aS = zero, dP = zero, dS = zero;
      mid_chunk(Ws, axh, axl, ayh, ayl, hrc, quad, aP, aS, dP, dS);
      {
        int hb = c * 32 + wq * 16 + quad * 4;
        float4 bv4 = *(const float4*)&b3d[hb];
        float4 pa, pd;
#pragma unroll
        for (int j = 0; j < 4; j++) {
          float p = aP[j] + aS[j] * INV2K + (&bv4.x)[j];
          float s = p > 0.f ? 1.f : SLP;
          (&pa.x)[j] = p * s;
          (&pd.x)[j] = s * (dP[j] + dS[j] * INV2K);
        }
        *(float4*)&A3F[swzF(ra, hb)] = pa;
        *(float4*)&D3F[swzF(ra, hb)] = pd;
      }
    }
  }
  __syncthreads();

  // ---- Layer 4 (512 threads: 64 rows x 8 col-groups)
  {
    int n = tid >> 3, oct = tid & 7;
    const float* w4d = W4 + d * Hh;
    float sr = 0.f, sd = 0.f;
#pragma unroll
    for (int i = 0; i < 4; i++) {
      int c = oct * 16 + i * 4;
      float4 va = *(const float4*)&A3F[swzF(n, c)];
      float4 vd = *(const float4*)&D3F[swzF(n, c)];
      float4 w = *(const float4*)&w4d[c];
      sr += va.x * w.x + va.y * w.y + va.z * w.z + va.w * w.w;
      sd += vd.x * w.x + vd.y * w.y + vd.z * w.z + vd.w * w.w;
    }
    sr += __shfl_xor(sr, 1); sr += __shfl_xor(sr, 2); sr += __shfl_xor(sr, 4);
    sd += __shfl_xor(sd, 1); sd += __shfl_xor(sd, 2); sd += __shfl_xor(sd, 4);
    if (oct == 0) {
      int ng = n0 + n;
      out_res[ng * 64 + d] = sr + b4[d];
      atomicAdd(&out_log[ng], logf(fabsf(sd) + 1e-8f));
    }
  }
}

// ---------------- fallback (no-ws path, 256 threads, raw weights) -----------
__device__ __forceinline__ void stage_wf(f16* WH, f16* WL,
                                         const float* __restrict__ g, int tid) {
  for (int i = tid; i < 2048; i += 256) {
    int h = i >> 5, k4 = (i & 31) << 2;
    float4 v = ((const float4*)g)[i];
    HL a = split(v.x), b = split(v.y), c = split(v.z), e = split(v.w);
    int o = swz(h, k4);
    *(f16x4*)&WH[o] = f16x4{a.h, b.h, c.h, e.h};
    *(f16x4*)&WL[o] = f16x4{a.l, b.l, c.l, e.l};
  }
}

__device__ __forceinline__ void mid_mfma_half(
    const f16* AH, const f16* AL, const f16* DH, const f16* DL,
    const f16* WH, const f16* WL, int nt, int wq, int l15, int quad,
    f32x4* aP, f32x4* aS, f32x4* dP, f32x4* dS) {
#pragma unroll
  for (int kc = 0; kc < 4; kc++) {
    int ko = kc * 32 + quad * 8;
    int ra = nt * 16 + l15;
    f16x8 xh = *(const f16x8*)&AH[swz(ra, ko)];
    f16x8 xl = *(const f16x8*)&AL[swz(ra, ko)];
    f16x8 yh = *(const f16x8*)&DH[swz(ra, ko)];
    f16x8 yl = *(const f16x8*)&DL[swz(ra, ko)];
#pragma unroll
    for (int c2 = 0; c2 < 2; c2++) {
      int hr = (2 * wq + c2) * 16 + l15;
      f16x8 wh = *(const f16x8*)&WH[swz(hr, ko)];
      f16x8 wl = *(const f16x8*)&WL[swz(hr, ko)];
      aP[c2] = MFMA(wh, xh, aP[c2]);
      aS[c2] = MFMA(wl, xh, aS[c2]);
      aS[c2] = MFMA(wh, xl, aS[c2]);
      dP[c2] = MFMA(wh, yh, dP[c2]);
      dS[c2] = MFMA(wl, yh, dS[c2]);
      dS[c2] = MFMA(wh, yl, dS[c2]);
    }
  }
}

__global__ __launch_bounds__(256, 2)
void np_prior_fb(const float* __restrict__ x,
                 const float* __restrict__ W1, const float* __restrict__ b1,
                 const float* __restrict__ W2, const float* __restrict__ b2,
                 const float* __restrict__ W3, const float* __restrict__ b3,
                 const float* __restrict__ W4, const float* __restrict__ b4,
                 float* __restrict__ out_res, float* __restrict__ out_log) {
  __shared__ float4 smem[4096];
  f16* AH = (f16*)smem;
  f16* AL = AH + NT * 128;
  f16* DH = AL + NT * 128;
  f16* DL = DH + NT * 128;
  f16* WHp = (f16*)((char*)smem + 32768);
  f16* WLp = WHp + 64 * 128;
  float* A3F = (float*)smem;
  float* D3F = (float*)((char*)smem + 16384);

  const int tid = threadIdx.x, d = blockIdx.y, n0 = blockIdx.x * NT;
  const int lane = tid & 63, wv = tid >> 6, l15 = lane & 15, quad = lane >> 4;
  const int nt = wv & 1, wq = wv >> 1;

  const float* W1d = W1 + d * Hh * 65;
  const float* b1d = b1 + d * Hh;
  const f32x4 zero = {0.f, 0.f, 0.f, 0.f};

  for (int i = tid; i < NT * 16; i += 256) {
    int n = i >> 4, k4 = (i & 15) << 2;
    int ng = n0 + n, bb = ng >> 8, tt = ng & 255;
    float4 v = *(const float4*)&x[(bb * 257 + tt) * 64 + k4];
    HL a = split(v.x), b = split(v.y), c = split(v.z), e = split(v.w);
    int o = swz(n, k4);
    *(f16x4*)&AH[o] = f16x4{a.h, b.h, c.h, e.h};
    *(f16x4*)&AL[o] = f16x4{a.l, b.l, c.l, e.l};
  }
  float xtv;
  {
    int ng = n0 + nt * 16 + l15, bb = ng >> 8, tt = ng & 255;
    xtv = x[(bb * 257 + tt + 1) * 64 + d];
  }
  for (int i = tid; i < 64 * 64; i += 256) {
    int h = i >> 6, k = i & 63;
    HL s = split(W1d[h * 65 + k]);
    int o = swz(h, k);
    WHp[o] = s.h; WLp[o] = s.l;
  }
  __syncthreads();

  f32x4 l1P[2][2], l1S[2][2];
  for (int hf = 0; hf < 2; hf++) {
    if (hf == 1) {
      __syncthreads();
      for (int i = tid; i < 64 * 64; i += 256) {
        int h = i >> 6, k = i & 63;
        HL s = split(W1d[(64 + h) * 65 + k]);
        int o = swz(h, k);
        WHp[o] = s.h; WLp[o] = s.l;
      }
      __syncthreads();
    }
    l1P[hf][0] = zero; l1P[hf][1] = zero;
    l1S[hf][0] = zero; l1S[hf][1] = zero;
#pragma unroll
    for (int kc = 0; kc < 2; kc++) {
      int ko = kc * 32 + quad * 8;
      f16x8 xh = *(const f16x8*)&AH[swz(nt * 16 + l15, ko)];
      f16x8 xl = *(const f16x8*)&AL[swz(nt * 16 + l15, ko)];
#pragma unroll
      for (int c2 = 0; c2 < 2; c2++) {
        int hr = (2 * wq + c2) * 16 + l15;
        f16x8 wh = *(const f16x8*)&WHp[swz(hr, ko)];
        f16x8 wl = *(const f16x8*)&WLp[swz(hr, ko)];
        l1P[hf][c2] = MFMA(wh, xh, l1P[hf][c2]);
        l1S[hf][c2] = MFMA(wl, xh, l1S[hf][c2]);
        l1S[hf][c2] = MFMA(wh, xl, l1S[hf][c2]);
      }
    }
  }
  __syncthreads();

  {
    int n = nt * 16 + l15;
#pragma unroll
    for (int hf = 0; hf < 2; hf++)
#pragma unroll
      for (int c2 = 0; c2 < 2; c2++) {
        int hb = hf * 64 + (2 * wq + c2) * 16 + quad * 4;
        f16x4 ah, al, dh, dl;
#pragma unroll
        for (int j = 0; j < 4; j++) {
          int h = hb + j;
          float w1j = W1d[h * 65 + 64];
          float p = l1P[hf][c2][j] + l1S[hf][c2][j] * INV2K + xtv * w1j + b1d[h];
          float s = p > 0.f ? 1.f : SLP;
          HL av = split(p * s), dv = split(s * w1j);
          ah[j] = av.h; al[j] = av.l; dh[j] = dv.h; dl[j] = dv.l;
        }
        int o = swz(n, hb);
        *(f16x4*)&AH[o] = ah; *(f16x4*)&AL[o] = al;
        *(f16x4*)&DH[o] = dh; *(f16x4*)&DL[o] = dl;
      }
  }
  stage_wf(WHp, WLp, W2 + d * Hh * Hh, tid);
  __syncthreads();

  f32x4 aP[2][2], aS[2][2], dP[2][2], dS[2][2];
  for (int hf = 0; hf < 2; hf++) {
    if (hf == 1) {
      __syncthreads();
      stage_wf(WHp, WLp, W2 + d * Hh * Hh + 64 * 128, tid);
      __syncthreads();
    }
    aP[hf][0] = zero; aP[hf][1] = zero; aS[hf][0] = zero; aS[hf][1] = zero;
    dP[hf][0] = zero; dP[hf][1] = zero; dS[hf][0] = zero; dS[hf][1] = zero;
    mid_mfma_half(AH, AL, DH, DL, WHp, WLp, nt, wq, l15, quad,
                  aP[hf], aS[hf], dP[hf], dS[hf]);
  }
  __syncthreads();

  {
    const float* b2d = b2 + d * Hh;
    int n = nt * 16 + l15;
#pragma unroll
    for (int hf = 0; hf < 2; hf++)
#pragma unroll
      for (int c2 = 0; c2 < 2; c2++) {
        int hb = hf * 64 + (2 * wq + c2) * 16 + quad * 4;
        f16x4 ah, al, dh, dl;
#pragma unroll
        for (int j = 0; j < 4; j++) {
          int h = hb + j;
          float p = aP[hf][c2][j] + aS[hf][c2][j] * INV2K + b2d[h];
          float s = p > 0.f ? 1.f : SLP;
          float dd = s * (dP[hf][c2][j] + dS[hf][c2][j] * INV2K);
          HL av = split(p * s), dv = split(dd);
          ah[j] = av.h; al[j] = av.l; dh[j] = dv.h; dl[j] = dv.l;
        }
        int o = swz(n, hb);
        *(f16x4*)&AH[o] = ah; *(f16x4*)&AL[o] = al;
        *(f16x4*)&DH[o] = dh; *(f16x4*)&DL[o] = dl;
      }
  }
  stage_wf(WHp, WLp, W3 + d * Hh * Hh, tid);
  __syncthreads();

  for (int hf = 0; hf < 2; hf++) {
    if (hf == 1) {
      __syncthreads();
      stage_wf(WHp, WLp, W3 + d * Hh * Hh + 64 * 128, tid);
      __syncthreads();
    }
    aP[hf][0] = zero; aP[hf][1] = zero; aS[hf][0] = zero; aS[hf][1] = zero;
    dP[hf][0] = zero; dP[hf][1] = zero; dS[hf][0] = zero; dS[hf][1] = zero;
    mid_mfma_half(AH, AL, DH, DL, WHp, WLp, nt, wq, l15, quad,
                  aP[hf], aS[hf], dP[hf], dS[hf]);
  }
  __syncthreads();

  {
    const float* b3d = b3 + d * Hh;
    int n = nt * 16 + l15;
#pragma unroll
    for (int hf = 0; hf < 2; hf++)
#pragma unroll
      for (int c2 = 0; c2 < 2; c2++) {
        int hb = hf * 64 + (2 * wq + c2) * 16 + quad * 4;
        float4 pa, pd;
#pragma unroll
        for (int j = 0; j < 4; j++) {
          int h = hb + j;
          float p = aP[hf][c2][j] + aS[hf][c2][j] * INV2K + b3d[h];
          float s = p > 0.f ? 1.f : SLP;
          (&pa.x)[j] = p * s;
          (&pd.x)[j] = s * (dP[hf][c2][j] + dS[hf][c2][j] * INV2K);
        }
        *(float4*)&A3F[swzF(n, hb)] = pa;
        *(float4*)&D3F[swzF(n, hb)] = pd;
      }
  }
  __syncthreads();

  {
    int n = tid >> 3, oct = tid & 7;
    const float* w4d = W4 + d * Hh;
    float sr = 0.f, sd = 0.f;
#pragma unroll
    for (int i = 0; i < 4; i++) {
      int c = oct * 16 + i * 4;
      float4 va = *(const float4*)&A3F[swzF(n, c)];
      float4 vd = *(const float4*)&D3F[swzF(n, c)];
      float4 w = *(const float4*)&w4d[c];
      sr += va.x * w.x + va.y * w.y + va.z * w.z + va.w * w.w;
      sd += vd.x * w.x + vd.y * w.y + vd.z * w.z + vd.w * w.w;
    }
    sr += __shfl_xor(sr, 1); sr += __shfl_xor(sr, 2); sr += __shfl_xor(sr, 4);
    sd += __shfl_xor(sd, 1); sd += __shfl_xor(sd, 2); sd += __shfl_xor(sd, 4);
    if (oct == 0) {
      int ng = n0 + n;
      out_res[ng * 64 + d] = sr + b4[d];
      atomicAdd(&out_log[ng], logf(fabsf(sd) + 1e-8f));
    }
  }
}

extern "C" void kernel_launch(void* const* d_in, const int* in_sizes, int n_in,
                              void* d_out, int out_size, void* d_ws, size_t ws_size,
                              hipStream_t stream) {
  (void)in_sizes; (void)n_in; (void)out_size;
  const float* x  = (const float*)d_in[0];
  const float* W1 = (const float*)d_in[1];
  const float* b1 = (const float*)d_in[2];
  const float* W2 = (const float*)d_in[3];
  const float* b2 = (const float*)d_in[4];
  const float* W3 = (const float*)d_in[5];
  const float* b3 = (const float*)d_in[6];
  const float* W4 = (const float*)d_in[7];
  const float* b4 = (const float*)d_in[8];

  float* out_res = (float*)d_out;
  float* out_log = out_res + Nn * Dd;

  static int big_lds = -1;  // -1 unknown, 1 ok, 0 failed
  if (big_lds < 0) {
    big_lds = (hipFuncSetAttribute(
                   (const void*)np_prior_v2,
                   hipFuncAttributeMaxDynamicSharedMemorySize, 81920) ==
               hipSuccess)
                  ? 1
                  : 0;
  }

  if (ws_size >= WS_NEEDED && big_lds == 1) {
    f16* wsf = (f16*)d_ws;
    float* w1lg = (float*)((char*)d_ws + W1L_OFF);
    prep_kernel<<<2560, 256, 0, stream>>>(W1, W2, W3, wsf, w1lg, out_log);
    dim3 grid(Nn / 64, Dd);
    np_prior_v2<<<grid, 512, 81920, stream>>>(x, wsf, w1lg, b1, b2, b3, W4,
                                              b4, out_res, out_log);
  } else {
    hipMemsetAsync(out_log, 0, Nn * sizeof(float), stream);
    dim3 grid(Nn / NT, Dd);
    np_prior_fb<<<grid, 256, 0, stream>>>(x, W1, b1, W2, b2, W3, b3, W4, b4,
                                          out_res, out_log);
  }
}